// Round 5
// baseline (959.145 us; speedup 1.0000x reference)
//
#include <hip/hip_runtime.h>
#include <math.h>

#define NN 2708
#define IC 1433
#define OC 128
#define NV (NN / 4)          // 677 int4/float4 per row (exact)
#define NNOC ((size_t)NN * OC)

// ---------------- zero the fp64 atomic targets (u1, s) ----------------
__global__ __launch_bounds__(256) void zero_dbl(double* d, int n) {
  int i = blockIdx.x * 256 + threadIdx.x;
  if (i < n) d[i] = 0.0;
}

// ---------------- w1 = W^T a1, w2 = W^T a2 (fp64) ----------------
__global__ __launch_bounds__(256) void wvec(const float* __restrict__ W, const float* __restrict__ a1,
                                            const float* __restrict__ a2,
                                            double* __restrict__ w1, double* __restrict__ w2) {
  int c = blockIdx.x * 256 + threadIdx.x;
  if (c >= IC) return;
  double s1 = 0.0, s2 = 0.0;
  for (int o = 0; o < OC; o++) {
    double w = (double)W[(size_t)o * IC + c];   // coalesced across c
    s1 = fma(w, (double)a1[o], s1);
    s2 = fma(w, (double)a2[o], s2);
  }
  w1[c] = s1; w2[c] = s2;
}

// ---------------- k1 = X@w1, k2 = X@w2 (fp64), one wave per row ----------------
__global__ __launch_bounds__(256) void xw(const float* __restrict__ X, const double* __restrict__ w1,
                                          const double* __restrict__ w2,
                                          double* __restrict__ k1, double* __restrict__ k2) {
  __shared__ double w1s[IC];
  __shared__ double w2s[IC];
  const int t = threadIdx.x;
  for (int c = t; c < IC; c += 256) { w1s[c] = w1[c]; w2s[c] = w2[c]; }
  __syncthreads();
  const int wave = t >> 6, lane = t & 63;
  const int i = blockIdx.x * 4 + wave;
  if (i >= NN) return;
  const float* Xi = X + (size_t)i * IC;
  double s1 = 0.0, s2 = 0.0;
  for (int c = lane; c < IC; c += 64) {   // scalar: X rows only 4B-aligned
    double x = (double)Xi[c];
    s1 = fma(x, w1s[c], s1);
    s2 = fma(x, w2s[c], s2);
  }
  for (int o = 32; o; o >>= 1) { s1 += __shfl_down(s1, o, 64); s2 += __shfl_down(s2, o, 64); }
  if (lane == 0) { k1[i] = s1; k2[i] = s2; }
}

// ---------------- K partials: Kp[split] = X @ W^T over k-chunk (fp32, no atomics) ----------------
__global__ __launch_bounds__(256) void gemmK(const float* __restrict__ X, const float* __restrict__ W,
                                             float* __restrict__ Kp, int chunk) {
  __shared__ float Xs[32][33];    // [row][k], +1 pad: conflict-free staging writes
  __shared__ float Ws[32][132];   // [k][col], +4 pad keeps float4 alignment
  const int t  = threadIdx.x;
  const int rb = blockIdx.x * 32;
  const int ks = blockIdx.y * chunk;
  const int ke = min(IC, ks + chunk);
  float* __restrict__ Ko = Kp + (size_t)blockIdx.y * NNOC;
  const int row0 = (t >> 5) * 4;
  const int col4 = (t & 31) * 4;
  float acc[4][4];
#pragma unroll
  for (int r = 0; r < 4; r++)
#pragma unroll
    for (int c = 0; c < 4; c++) acc[r][c] = 0.f;

  for (int kb = ks; kb < ke; kb += 32) {
#pragma unroll
    for (int it = 0; it < 4; it++) {          // X tile 32x32
      int idx = t + it * 256;
      int r = idx >> 5, c = idx & 31;
      int gr = rb + r, gc = kb + c;
      Xs[r][c] = (gr < NN && gc < ke) ? X[(size_t)gr * IC + gc] : 0.f;
    }
#pragma unroll
    for (int it = 0; it < 16; it++) {         // W tile 128x32 -> Ws[k][col]
      int idx = t + it * 256;
      int o = idx >> 5, c = idx & 31;
      int gc = kb + c;
      Ws[c][o] = (gc < ke) ? W[(size_t)o * IC + gc] : 0.f;
    }
    __syncthreads();
#pragma unroll
    for (int kk = 0; kk < 32; kk++) {
      const float4 w4 = *reinterpret_cast<const float4*>(&Ws[kk][col4]);
      float x0 = Xs[row0 + 0][kk];            // wave-broadcast reads
      float x1 = Xs[row0 + 1][kk];
      float x2 = Xs[row0 + 2][kk];
      float x3 = Xs[row0 + 3][kk];
      acc[0][0] = fmaf(x0, w4.x, acc[0][0]); acc[0][1] = fmaf(x0, w4.y, acc[0][1]);
      acc[0][2] = fmaf(x0, w4.z, acc[0][2]); acc[0][3] = fmaf(x0, w4.w, acc[0][3]);
      acc[1][0] = fmaf(x1, w4.x, acc[1][0]); acc[1][1] = fmaf(x1, w4.y, acc[1][1]);
      acc[1][2] = fmaf(x1, w4.z, acc[1][2]); acc[1][3] = fmaf(x1, w4.w, acc[1][3]);
      acc[2][0] = fmaf(x2, w4.x, acc[2][0]); acc[2][1] = fmaf(x2, w4.y, acc[2][1]);
      acc[2][2] = fmaf(x2, w4.z, acc[2][2]); acc[2][3] = fmaf(x2, w4.w, acc[2][3]);
      acc[3][0] = fmaf(x3, w4.x, acc[3][0]); acc[3][1] = fmaf(x3, w4.y, acc[3][1]);
      acc[3][2] = fmaf(x3, w4.z, acc[3][2]); acc[3][3] = fmaf(x3, w4.w, acc[3][3]);
    }
    __syncthreads();
  }
#pragma unroll
  for (int r = 0; r < 4; r++) {
    int gr = rb + row0 + r;
    if (gr < NN) {
      float4 v = make_float4(acc[r][0], acc[r][1], acc[r][2], acc[r][3]);
      *reinterpret_cast<float4*>(&Ko[(size_t)gr * OC + col4]) = v;
    }
  }
}

// ---------------- u1 = U^T@k1, s = U^T@1 (fp64, float4 cols, row-chunked atomics) ----------------
__global__ __launch_bounds__(256) void ut_reduce(const float4* __restrict__ U4, const double* __restrict__ k1,
                                                 double* __restrict__ u1, double* __restrict__ s) {
  int c4 = blockIdx.x * 256 + threadIdx.x;
  if (c4 >= NV) return;
  int r0 = blockIdx.y * 32;
  int r1 = min(NN, r0 + 32);
  double au0 = 0, au1_ = 0, au2 = 0, au3 = 0, as0 = 0, as1 = 0, as2 = 0, as3 = 0;
  for (int r = r0; r < r1; r++) {
    float4 u = U4[(size_t)r * NV + c4];
    double kr = k1[r];
    au0 = fma((double)u.x, kr, au0); au1_ = fma((double)u.y, kr, au1_);
    au2 = fma((double)u.z, kr, au2); au3 = fma((double)u.w, kr, au3);
    as0 += (double)u.x; as1 += (double)u.y; as2 += (double)u.z; as3 += (double)u.w;
  }
  int c = c4 * 4;
  atomicAdd(&u1[c + 0], au0); atomicAdd(&u1[c + 1], au1_);
  atomicAdd(&u1[c + 2], au2); atomicAdd(&u1[c + 3], au3);
  atomicAdd(&s[c + 0], as0);  atomicAdd(&s[c + 1], as1);
  atomicAdd(&s[c + 2], as2);  atomicAdd(&s[c + 3], as3);
}

// ---------------- p = U@(lmbd*u1), q = U@(lmbd*s) (fp64, float4), one wave per row ----------------
__global__ __launch_bounds__(256) void uv_kernel(const float4* __restrict__ U4, const float4* __restrict__ L4,
                                                 const double2* __restrict__ u1d, const double2* __restrict__ sd,
                                                 double* __restrict__ p, double* __restrict__ q) {
  const int t = threadIdx.x;
  const int wave = t >> 6, lane = t & 63;
  const int r = blockIdx.x * 4 + wave;
  if (r >= NN) return;
  const float4* Ur = U4 + (size_t)r * NV;
  double ap = 0.0, aq = 0.0;
  for (int c4 = lane; c4 < NV; c4 += 64) {
    float4 u = Ur[c4];
    float4 lm = L4[c4];
    double2 ua = u1d[c4 * 2], ub = u1d[c4 * 2 + 1];
    double2 sa = sd[c4 * 2],  sb = sd[c4 * 2 + 1];
    ap = fma((double)u.x, (double)lm.x * ua.x, ap);
    ap = fma((double)u.y, (double)lm.y * ua.y, ap);
    ap = fma((double)u.z, (double)lm.z * ub.x, ap);
    ap = fma((double)u.w, (double)lm.w * ub.y, ap);
    aq = fma((double)u.x, (double)lm.x * sa.x, aq);
    aq = fma((double)u.y, (double)lm.y * sa.y, aq);
    aq = fma((double)u.z, (double)lm.z * sb.x, aq);
    aq = fma((double)u.w, (double)lm.w * sb.y, aq);
  }
  for (int o = 32; o; o >>= 1) { ap += __shfl_down(ap, o, 64); aq += __shfl_down(aq, o, 64); }
  if (lane == 0) { p[r] = ap; q[r] = aq; }
}

// ---------------- fused masked softmax + H, single A-pass, candidate compaction ----------------
__global__ __launch_bounds__(256) void softmaxH(const int4* __restrict__ A4, const double2* __restrict__ k2d,
                                                const double* __restrict__ p, const double* __restrict__ q,
                                                const float* __restrict__ Kp, float* __restrict__ H, int nsplit) {
  __shared__ float el[NN];        // candidate e (later overwritten by w)  10.8 KB
  __shared__ short jl[NN];        // candidate j                            5.4 KB
  __shared__ float hpart[2][128];
  __shared__ double redd[4];
  __shared__ float redf[4];
  __shared__ int nnz;
  __shared__ double m_sh;
  __shared__ float sum_sh;

  const int i = blockIdx.x;
  const int t = threadIdx.x;
  const int wave = t >> 6, lane = t & 63;
  if (t == 0) nnz = 0;
  const double pi = p[i], qi = q[i];
  const int4* Arow = A4 + (size_t)i * NV;
  __syncthreads();

  // single scan: online max + candidate compaction (criterion uses pre-update runmax,
  // which only grows => no candidate within 30 of the final max is missed)
  double runmax = -1e300;
  for (int v = t; v < NV; v += 256) {
    int4 a = Arow[v];
    double2 kA = k2d[2 * v], kB = k2d[2 * v + 1];
    int j = 4 * v;
    if (a.x) { double e = fabs(fma(qi, kA.x, pi));
      if (e > runmax - 30.0) { int pos = atomicAdd(&nnz, 1); jl[pos] = (short)j;       el[pos] = (float)e; runmax = fmax(runmax, e); } }
    if (a.y) { double e = fabs(fma(qi, kA.y, pi));
      if (e > runmax - 30.0) { int pos = atomicAdd(&nnz, 1); jl[pos] = (short)(j + 1); el[pos] = (float)e; runmax = fmax(runmax, e); } }
    if (a.z) { double e = fabs(fma(qi, kB.x, pi));
      if (e > runmax - 30.0) { int pos = atomicAdd(&nnz, 1); jl[pos] = (short)(j + 2); el[pos] = (float)e; runmax = fmax(runmax, e); } }
    if (a.w) { double e = fabs(fma(qi, kB.y, pi));
      if (e > runmax - 30.0) { int pos = atomicAdd(&nnz, 1); jl[pos] = (short)(j + 3); el[pos] = (float)e; runmax = fmax(runmax, e); } }
  }
  for (int o = 32; o; o >>= 1) runmax = fmax(runmax, __shfl_down(runmax, o, 64));
  if (lane == 0) redd[wave] = runmax;
  __syncthreads();
  if (t == 0) m_sh = fmax(fmax(redd[0], redd[1]), fmax(redd[2], redd[3]));
  __syncthreads();
  const double mi = m_sh;
  const int nn = nnz;

  // weights from stored e (exact-max in fp64; e stored to 1e-3 abs => w rel err ~1e-3, negligible)
  float sw = 0.f;
  for (int it = t; it < nn; it += 256) {
    float w = __expf((float)((double)el[it] - mi));
    el[it] = w;
    sw += w;
  }
  for (int o = 32; o; o >>= 1) sw += __shfl_down(sw, o, 64);
  if (lane == 0) redf[wave] = sw;
  __syncthreads();
  if (t == 0) sum_sh = (redf[0] + redf[1]) + (redf[2] + redf[3]);
  __syncthreads();

  // H[i] = sum_j w_j * K[j] / sumw  (sum split-K partials during gather; nnz-effective is tiny)
  const float inv = 1.0f / sum_sh;
  const int ch = t & 127, g = t >> 7;
  float hacc = 0.f;
  for (int it = g; it < nn; it += 2) {
    float w = el[it];
    if (w > 1e-10f) {
      size_t off = (size_t)jl[it] * OC + ch;
      float kv = 0.f;
      for (int ps = 0; ps < nsplit; ps++) kv += Kp[ps * NNOC + off];
      hacc = fmaf(w, kv, hacc);
    }
  }
  hpart[g][ch] = hacc;
  __syncthreads();
  if (t < 128) H[(size_t)i * OC + t] = (hpart[0][t] + hpart[1][t]) * inv;
}

extern "C" void kernel_launch(void* const* d_in, const int* in_sizes, int n_in,
                              void* d_out, int out_size, void* d_ws, size_t ws_size,
                              hipStream_t stream) {
  const float* X    = (const float*)d_in[0];
  const int*   A    = (const int*)d_in[1];
  const float* U    = (const float*)d_in[2];
  const float* W    = (const float*)d_in[3];
  const float* a1   = (const float*)d_in[4];
  const float* a2   = (const float*)d_in[5];
  const float* lmbd = (const float*)d_in[6];
  float* H = (float*)d_out;

  // workspace: nsplit K-partials (fp32) then fp64 scratch
  const size_t dbl_bytes = (size_t)(6 * NN + 2 * IC) * 8;
  int nsplit = 4;
  while (nsplit > 1 && (size_t)nsplit * NNOC * 4 + dbl_bytes > ws_size) nsplit >>= 1;
  const int chunk = (IC + nsplit - 1) / nsplit;

  float* Kp = (float*)d_ws;
  double* dbl = (double*)((char*)d_ws + (size_t)nsplit * NNOC * 4);  // 16B-aligned
  double* k1 = dbl;
  double* k2 = k1 + NN;
  double* u1 = k2 + NN;
  double* sC = u1 + NN;
  double* p  = sC + NN;
  double* q  = p  + NN;
  double* w1 = q  + NN;
  double* w2 = w1 + IC;

  zero_dbl<<<(2 * NN + 255) / 256, 256, 0, stream>>>(u1, 2 * NN);  // u1 and sC (contiguous)
  wvec<<<(IC + 255) / 256, 256, 0, stream>>>(W, a1, a2, w1, w2);
  xw<<<NN / 4, 256, 0, stream>>>(X, w1, w2, k1, k2);
  gemmK<<<dim3((NN + 31) / 32, nsplit), 256, 0, stream>>>(X, W, Kp, chunk);
  ut_reduce<<<dim3((NV + 255) / 256, (NN + 31) / 32), 256, 0, stream>>>((const float4*)U, k1, u1, sC);
  uv_kernel<<<NN / 4, 256, 0, stream>>>((const float4*)U, (const float4*)lmbd,
                                        (const double2*)u1, (const double2*)sC, p, q);
  softmaxH<<<NN, 256, 0, stream>>>((const int4*)A, (const double2*)k2, p, q, Kp, H, nsplit);
}

// Round 6
// 720.863 us; speedup vs baseline: 1.3306x; 1.3306x over previous
//
#include <hip/hip_runtime.h>
#include <math.h>

#define NN 2708
#define IC 1433
#define OC 128
#define NV (NN / 4)          // 677 float4/int4 per row (exact)
#define NNOC ((size_t)NN * OC)
#define NB 4096              // sort buckets

// ---------------- zero helpers ----------------
__global__ __launch_bounds__(256) void zero_dbl(double* d, int n) {
  int i = blockIdx.x * 256 + threadIdx.x;
  if (i < n) d[i] = 0.0;
}
__global__ __launch_bounds__(256) void zero_int(int* d, int n) {
  int i = blockIdx.x * 256 + threadIdx.x;
  if (i < n) d[i] = 0;
}

// ---------------- w1 = W^T a1, w2 = W^T a2 (fp64) ----------------
__global__ __launch_bounds__(256) void wvec(const float* __restrict__ W, const float* __restrict__ a1,
                                            const float* __restrict__ a2,
                                            double* __restrict__ w1, double* __restrict__ w2) {
  int c = blockIdx.x * 256 + threadIdx.x;
  if (c >= IC) return;
  double s1 = 0.0, s2 = 0.0;
  for (int o = 0; o < OC; o++) {
    double w = (double)W[(size_t)o * IC + c];
    s1 = fma(w, (double)a1[o], s1);
    s2 = fma(w, (double)a2[o], s2);
  }
  w1[c] = s1; w2[c] = s2;
}

// ---------------- k1 = X@w1, k2 = X@w2 (fp64), one wave per row ----------------
__global__ __launch_bounds__(256) void xw(const float* __restrict__ X, const double* __restrict__ w1,
                                          const double* __restrict__ w2,
                                          double* __restrict__ k1, double* __restrict__ k2) {
  __shared__ double w1s[IC];
  __shared__ double w2s[IC];
  const int t = threadIdx.x;
  for (int c = t; c < IC; c += 256) { w1s[c] = w1[c]; w2s[c] = w2[c]; }
  __syncthreads();
  const int wave = t >> 6, lane = t & 63;
  const int i = blockIdx.x * 4 + wave;
  if (i >= NN) return;
  const float* Xi = X + (size_t)i * IC;
  double s1 = 0.0, s2 = 0.0;
  for (int c = lane; c < IC; c += 64) {
    double x = (double)Xi[c];
    s1 = fma(x, w1s[c], s1);
    s2 = fma(x, w2s[c], s2);
  }
  for (int o = 32; o; o >>= 1) { s1 += __shfl_down(s1, o, 64); s2 += __shfl_down(s2, o, 64); }
  if (lane == 0) { k1[i] = s1; k2[i] = s2; }
}

// ---------------- K partials: Kp[split] = X @ W^T over k-chunk (fp32) ----------------
__global__ __launch_bounds__(256) void gemmK(const float* __restrict__ X, const float* __restrict__ W,
                                             float* __restrict__ Kp, int chunk) {
  __shared__ float Xs[32][33];
  __shared__ float Ws[32][132];
  const int t  = threadIdx.x;
  const int rb = blockIdx.x * 32;
  const int ks = blockIdx.y * chunk;
  const int ke = min(IC, ks + chunk);
  float* __restrict__ Ko = Kp + (size_t)blockIdx.y * NNOC;
  const int row0 = (t >> 5) * 4;
  const int col4 = (t & 31) * 4;
  float acc[4][4];
#pragma unroll
  for (int r = 0; r < 4; r++)
#pragma unroll
    for (int c = 0; c < 4; c++) acc[r][c] = 0.f;

  for (int kb = ks; kb < ke; kb += 32) {
#pragma unroll
    for (int it = 0; it < 4; it++) {
      int idx = t + it * 256;
      int r = idx >> 5, c = idx & 31;
      int gr = rb + r, gc = kb + c;
      Xs[r][c] = (gr < NN && gc < ke) ? X[(size_t)gr * IC + gc] : 0.f;
    }
#pragma unroll
    for (int it = 0; it < 16; it++) {
      int idx = t + it * 256;
      int o = idx >> 5, c = idx & 31;
      int gc = kb + c;
      Ws[c][o] = (gc < ke) ? W[(size_t)o * IC + gc] : 0.f;
    }
    __syncthreads();
#pragma unroll
    for (int kk = 0; kk < 32; kk++) {
      const float4 w4 = *reinterpret_cast<const float4*>(&Ws[kk][col4]);
      float x0 = Xs[row0 + 0][kk];
      float x1 = Xs[row0 + 1][kk];
      float x2 = Xs[row0 + 2][kk];
      float x3 = Xs[row0 + 3][kk];
      acc[0][0] = fmaf(x0, w4.x, acc[0][0]); acc[0][1] = fmaf(x0, w4.y, acc[0][1]);
      acc[0][2] = fmaf(x0, w4.z, acc[0][2]); acc[0][3] = fmaf(x0, w4.w, acc[0][3]);
      acc[1][0] = fmaf(x1, w4.x, acc[1][0]); acc[1][1] = fmaf(x1, w4.y, acc[1][1]);
      acc[1][2] = fmaf(x1, w4.z, acc[1][2]); acc[1][3] = fmaf(x1, w4.w, acc[1][3]);
      acc[2][0] = fmaf(x2, w4.x, acc[2][0]); acc[2][1] = fmaf(x2, w4.y, acc[2][1]);
      acc[2][2] = fmaf(x2, w4.z, acc[2][2]); acc[2][3] = fmaf(x2, w4.w, acc[2][3]);
      acc[3][0] = fmaf(x3, w4.x, acc[3][0]); acc[3][1] = fmaf(x3, w4.y, acc[3][1]);
      acc[3][2] = fmaf(x3, w4.z, acc[3][2]); acc[3][3] = fmaf(x3, w4.w, acc[3][3]);
    }
    __syncthreads();
  }
#pragma unroll
  for (int r = 0; r < 4; r++) {
    int gr = rb + row0 + r;
    if (gr < NN) {
      float4 v = make_float4(acc[r][0], acc[r][1], acc[r][2], acc[r][3]);
      *reinterpret_cast<float4*>(&Ko[(size_t)gr * OC + col4]) = v;
    }
  }
}

// ---------------- merge split-K partials ----------------
__global__ __launch_bounds__(256) void mergeK(const float* __restrict__ Kp, float* __restrict__ Kf) {
  size_t i = (size_t)blockIdx.x * 256 + threadIdx.x;
  if (i < NNOC) Kf[i] = Kp[i] + Kp[NNOC + i];
}

// ---------------- u1 = U^T@k1, s = U^T@1 (fp64, float4 cols) ----------------
__global__ __launch_bounds__(256) void ut_reduce(const float4* __restrict__ U4, const double* __restrict__ k1,
                                                 double* __restrict__ u1, double* __restrict__ s) {
  int c4 = blockIdx.x * 256 + threadIdx.x;
  if (c4 >= NV) return;
  int r0 = blockIdx.y * 32;
  int r1 = min(NN, r0 + 32);
  double au0 = 0, au1_ = 0, au2 = 0, au3 = 0, as0 = 0, as1 = 0, as2 = 0, as3 = 0;
  for (int r = r0; r < r1; r++) {
    float4 u = U4[(size_t)r * NV + c4];
    double kr = k1[r];
    au0 = fma((double)u.x, kr, au0); au1_ = fma((double)u.y, kr, au1_);
    au2 = fma((double)u.z, kr, au2); au3 = fma((double)u.w, kr, au3);
    as0 += (double)u.x; as1 += (double)u.y; as2 += (double)u.z; as3 += (double)u.w;
  }
  int c = c4 * 4;
  atomicAdd(&u1[c + 0], au0); atomicAdd(&u1[c + 1], au1_);
  atomicAdd(&u1[c + 2], au2); atomicAdd(&u1[c + 3], au3);
  atomicAdd(&s[c + 0], as0);  atomicAdd(&s[c + 1], as1);
  atomicAdd(&s[c + 2], as2);  atomicAdd(&s[c + 3], as3);
}

// ---------------- p = U@(lmbd*u1), q = U@(lmbd*s) (fp64), one wave per row ----------------
__global__ __launch_bounds__(256) void uv_kernel(const float4* __restrict__ U4, const float4* __restrict__ L4,
                                                 const double2* __restrict__ u1d, const double2* __restrict__ sd,
                                                 double* __restrict__ p, double* __restrict__ q) {
  const int t = threadIdx.x;
  const int wave = t >> 6, lane = t & 63;
  const int r = blockIdx.x * 4 + wave;
  if (r >= NN) return;
  const float4* Ur = U4 + (size_t)r * NV;
  double ap = 0.0, aq = 0.0;
  for (int c4 = lane; c4 < NV; c4 += 64) {
    float4 u = Ur[c4];
    float4 lm = L4[c4];
    double2 ua = u1d[c4 * 2], ub = u1d[c4 * 2 + 1];
    double2 sa = sd[c4 * 2],  sb = sd[c4 * 2 + 1];
    ap = fma((double)u.x, (double)lm.x * ua.x, ap);
    ap = fma((double)u.y, (double)lm.y * ua.y, ap);
    ap = fma((double)u.z, (double)lm.z * ub.x, ap);
    ap = fma((double)u.w, (double)lm.w * ub.y, ap);
    aq = fma((double)u.x, (double)lm.x * sa.x, aq);
    aq = fma((double)u.y, (double)lm.y * sa.y, aq);
    aq = fma((double)u.z, (double)lm.z * sb.x, aq);
    aq = fma((double)u.w, (double)lm.w * sb.y, aq);
  }
  for (int o = 32; o; o >>= 1) { ap += __shfl_down(ap, o, 64); aq += __shfl_down(aq, o, 64); }
  if (lane == 0) { p[r] = ap; q[r] = aq; }
}

// ---------------- sort pipeline: min/max, histogram, scan, scatter ----------------
__global__ __launch_bounds__(256) void minmax_k2(const double* __restrict__ k2d, double* __restrict__ hdr) {
  __shared__ double smn[4], smx[4];
  int t = threadIdx.x, wv = t >> 6, ln = t & 63;
  double mn = 1e300, mx = -1e300;
  for (int j = t; j < NN; j += 256) { double v = k2d[j]; mn = fmin(mn, v); mx = fmax(mx, v); }
  for (int o = 32; o; o >>= 1) { mn = fmin(mn, __shfl_xor(mn, o, 64)); mx = fmax(mx, __shfl_xor(mx, o, 64)); }
  if (ln == 0) { smn[wv] = mn; smx[wv] = mx; }
  __syncthreads();
  if (t == 0) {
    hdr[0] = fmin(fmin(smn[0], smn[1]), fmin(smn[2], smn[3]));
    hdr[1] = fmax(fmax(smx[0], smx[1]), fmax(smx[2], smx[3]));
  }
}

__device__ __forceinline__ int bucket_of(double v, double minv, double scale) {
  int b = (int)((v - minv) * scale);
  return min(NB - 1, max(0, b));
}

__global__ __launch_bounds__(256) void hist_k2(const double* __restrict__ k2d, const double* __restrict__ hdr,
                                               int* __restrict__ hist) {
  int j = blockIdx.x * 256 + threadIdx.x;
  if (j >= NN) return;
  double minv = hdr[0];
  double scale = NB / fmax(hdr[1] - minv, 1e-30);
  atomicAdd(&hist[bucket_of(k2d[j], minv, scale)], 1);
}

__global__ __launch_bounds__(1024) void scan_hist(const int* __restrict__ hist, int* __restrict__ off) {
  __shared__ int ps[1024];
  int t = threadIdx.x;
  int4 v = ((const int4*)hist)[t];
  int s = v.x + v.y + v.z + v.w;
  ps[t] = s;
  __syncthreads();
  for (int d = 1; d < 1024; d <<= 1) {
    int x = (t >= d) ? ps[t - d] : 0;
    __syncthreads();
    ps[t] += x;
    __syncthreads();
  }
  int excl = ps[t] - s;
  int4 o;
  o.x = excl; o.y = excl + v.x; o.z = o.y + v.y; o.w = o.z + v.z;
  ((int4*)off)[t] = o;
}

__global__ __launch_bounds__(256) void scatter_k2(const double* __restrict__ k2d, const double* __restrict__ hdr,
                                                  int* __restrict__ off, int* __restrict__ sortedj,
                                                  double* __restrict__ kvd) {
  int j = blockIdx.x * 256 + threadIdx.x;
  if (j >= NN) return;
  double minv = hdr[0];
  double scale = NB / fmax(hdr[1] - minv, 1e-30);
  int pos = atomicAdd(&off[bucket_of(k2d[j], minv, scale)], 1);
  sortedj[pos] = j;
  kvd[pos] = k2d[j];
}

// ---------------- softmax+H via sorted-tail enumeration, one wave per row ----------------
// e_ij = |p_i + q_i*k2_j| is monotone in k2 on each side of |.|: only the two sorted
// tails hold weights above exp(-36). Walk inward with the bucket-jitter margin;
// probe A membership only for walked positions; ballot-compact candidates (no LDS atomics).
__global__ __launch_bounds__(128) void softmaxH(const int* __restrict__ A,
                                                const double* __restrict__ p, const double* __restrict__ q,
                                                const double* __restrict__ kvd, const int* __restrict__ sortedj,
                                                const double* __restrict__ hdr,
                                                const float* __restrict__ K, float* __restrict__ H) {
  __shared__ float vfs[2][NN];
  __shared__ short jss[2][NN];
  const int wv = threadIdx.x >> 6, lane = threadIdx.x & 63;
  const int i = blockIdx.x * 2 + wv;
  if (i >= NN) return;
  float* vfw = vfs[wv];
  short* jsw = jss[wv];
  const double pi = p[i], qi = q[i];
  const double bw = (hdr[1] - hdr[0]) * (1.0 / NB);
  const double margin = 36.0 + 2.0 * fabs(qi) * bw;
  const int* Arow = A + (size_t)i * NN;
  const bool sgn = (qi >= 0.0);
  const unsigned long long ltmask = (1ull << lane) - 1ull;
  int nlist = 0;
  double m_lb = -1e300;

  // WALK A: positions where v = pi + qi*k2 is largest
  const int maxR = (NN + 63) / 64;
  int roundsA = 0;
  for (int r = 0; r < maxR; r++) {
    int idx = r * 64 + lane;
    bool ok = idx < NN;
    double v = -1e300; int j = 0; int a = 0;
    if (ok) {
      int pos = sgn ? (NN - 1 - idx) : idx;
      v = fma(qi, kvd[pos], pi);
      j = sortedj[pos];
      a = Arow[j];
    }
    bool isn = ok && (a != 0);
    unsigned long long mask = __ballot(isn);
    int off = __popcll(mask & ltmask);
    if (isn) { jsw[nlist + off] = (short)j; vfw[nlist + off] = (float)v; }
    nlist += __popcll(mask);
    double fv = isn ? fabs(v) : -1e300;
    for (int o = 32; o; o >>= 1) fv = fmax(fv, __shfl_xor(fv, o, 64));
    m_lb = fmax(m_lb, fv);
    double rv = ok ? v : -1e300;
    for (int o = 32; o; o >>= 1) rv = fmax(rv, __shfl_xor(rv, o, 64));
    roundsA = r + 1;
    if (rv < m_lb - margin) break;
  }
  int coveredA = min(NN, roundsA * 64);
  int remB = NN - coveredA;

  // WALK B: positions where v is smallest (e = -v side)
  for (int r = 0; r * 64 < remB; r++) {
    int idx = r * 64 + lane;
    bool ok = idx < remB;
    double v = 1e300; int j = 0; int a = 0;
    if (ok) {
      int pos = sgn ? idx : (NN - 1 - idx);
      v = fma(qi, kvd[pos], pi);
      j = sortedj[pos];
      a = Arow[j];
    }
    bool isn = ok && (a != 0);
    unsigned long long mask = __ballot(isn);
    int off = __popcll(mask & ltmask);
    if (isn) { jsw[nlist + off] = (short)j; vfw[nlist + off] = (float)v; }
    nlist += __popcll(mask);
    double fv = isn ? fabs(v) : -1e300;
    for (int o = 32; o; o >>= 1) fv = fmax(fv, __shfl_xor(fv, o, 64));
    m_lb = fmax(m_lb, fv);
    double rv = ok ? (-v) : -1e300;
    for (int o = 32; o; o >>= 1) rv = fmax(rv, __shfl_xor(rv, o, 64));
    if (rv < m_lb - margin) break;
  }

  // weights (m_lb == exact masked max: its argmax is provably in the list)
  const float fm = (float)m_lb;
  float sw = 0.f;
  for (int c = lane; c < nlist; c += 64) {
    float w = __expf(fabsf(vfw[c]) - fm);
    vfw[c] = w;
    sw += w;
  }
  for (int o = 32; o; o >>= 1) sw += __shfl_xor(sw, o, 64);

  // gather H[i] = sum w*K[j] / sw
  const float cut = sw * 1e-9f;
  float a0 = 0.f, a1 = 0.f;
  for (int c = 0; c < nlist; c++) {
    float w = vfw[c];
    if (w > cut) {
      const float* Kr = K + (size_t)jsw[c] * OC;
      a0 = fmaf(w, Kr[lane], a0);
      a1 = fmaf(w, Kr[64 + lane], a1);
    }
  }
  const float inv = 1.f / sw;
  H[(size_t)i * OC + lane] = a0 * inv;
  H[(size_t)i * OC + 64 + lane] = a1 * inv;
}

extern "C" void kernel_launch(void* const* d_in, const int* in_sizes, int n_in,
                              void* d_out, int out_size, void* d_ws, size_t ws_size,
                              hipStream_t stream) {
  const float* X    = (const float*)d_in[0];
  const int*   A    = (const int*)d_in[1];
  const float* U    = (const float*)d_in[2];
  const float* W    = (const float*)d_in[3];
  const float* a1   = (const float*)d_in[4];
  const float* a2   = (const float*)d_in[5];
  const float* lmbd = (const float*)d_in[6];
  float* H = (float*)d_out;

  const size_t aux_bytes = (size_t)(7 * NN + 2 * IC + 2) * 8 + (size_t)(2 * NB + NN) * 4;
  char* base = (char*)d_ws;
  int nsplit;
  float *Kp, *Kf;
  size_t koff;
  if (ws_size >= 3 * NNOC * 4 + aux_bytes) {
    nsplit = 2;
    Kp = (float*)base;
    Kf = (float*)(base + 2 * NNOC * 4);
    koff = 3 * NNOC * 4;
  } else {
    nsplit = 1;
    Kp = Kf = (float*)base;
    koff = NNOC * 4;
  }
  double* dbl = (double*)(base + koff);
  double* k1  = dbl;            // NN
  double* k2  = k1 + NN;        // NN
  double* u1  = k2 + NN;        // NN
  double* sC  = u1 + NN;        // NN
  double* p   = sC + NN;        // NN
  double* q   = p  + NN;        // NN
  double* kvd = q  + NN;        // NN
  double* w1  = kvd + NN;       // IC
  double* w2  = w1 + IC;        // IC
  double* hdr = w2 + IC;        // 2
  int* hist    = (int*)(hdr + 2);  // NB
  int* offb    = hist + NB;        // NB
  int* sortedj = offb + NB;        // NN

  const int chunk = (IC + nsplit - 1) / nsplit;

  zero_dbl<<<(2 * NN + 255) / 256, 256, 0, stream>>>(u1, 2 * NN);
  zero_int<<<(NB + 255) / 256, 256, 0, stream>>>(hist, NB);
  wvec<<<(IC + 255) / 256, 256, 0, stream>>>(W, a1, a2, w1, w2);
  xw<<<NN / 4, 256, 0, stream>>>(X, w1, w2, k1, k2);
  gemmK<<<dim3((NN + 31) / 32, nsplit), 256, 0, stream>>>(X, W, Kp, chunk);
  if (nsplit == 2)
    mergeK<<<(int)((NNOC + 255) / 256), 256, 0, stream>>>(Kp, Kf);
  ut_reduce<<<dim3((NV + 255) / 256, (NN + 31) / 32), 256, 0, stream>>>((const float4*)U, k1, u1, sC);
  uv_kernel<<<NN / 4, 256, 0, stream>>>((const float4*)U, (const float4*)lmbd,
                                        (const double2*)u1, (const double2*)sC, p, q);
  minmax_k2<<<1, 256, 0, stream>>>(k2, hdr);
  hist_k2<<<(NN + 255) / 256, 256, 0, stream>>>(k2, hdr, hist);
  scan_hist<<<1, 1024, 0, stream>>>(hist, offb);
  scatter_k2<<<(NN + 255) / 256, 256, 0, stream>>>(k2, hdr, offb, sortedj, kvd);
  softmaxH<<<NN / 2, 128, 0, stream>>>(A, p, q, kvd, sortedj, hdr, Kf, H);
}

// Round 7
// 358.186 us; speedup vs baseline: 2.6778x; 2.0125x over previous
//
#include <hip/hip_runtime.h>
#include <math.h>

#define NN 2708
#define IC 1433
#define OC 128
#define NV (NN / 4)          // 677 float4/int4 per row (exact)
#define NNOC ((size_t)NN * OC)
#define NB 4096              // sort buckets

// ---------------- zero fp64 targets + int histogram in one launch ----------------
__global__ __launch_bounds__(256) void zero_ws2(double* d, int nd, int* hi, int nh) {
  int i = blockIdx.x * 256 + threadIdx.x;
  if (i < nd) d[i] = 0.0;
  if (i < nh) hi[i] = 0;
}

// ---------------- w1 = W^T a1, w2 = W^T a2 (fp64) ----------------
__global__ __launch_bounds__(256) void wvec(const float* __restrict__ W, const float* __restrict__ a1,
                                            const float* __restrict__ a2,
                                            double* __restrict__ w1, double* __restrict__ w2) {
  int c = blockIdx.x * 256 + threadIdx.x;
  if (c >= IC) return;
  double s1 = 0.0, s2 = 0.0;
  for (int o = 0; o < OC; o++) {
    double w = (double)W[(size_t)o * IC + c];
    s1 = fma(w, (double)a1[o], s1);
    s2 = fma(w, (double)a2[o], s2);
  }
  w1[c] = s1; w2[c] = s2;
}

// ---------------- k1 = X@w1, k2 = X@w2 (fp64), one wave per row ----------------
__global__ __launch_bounds__(256) void xw(const float* __restrict__ X, const double* __restrict__ w1,
                                          const double* __restrict__ w2,
                                          double* __restrict__ k1, double* __restrict__ k2) {
  __shared__ double w1s[IC];
  __shared__ double w2s[IC];
  const int t = threadIdx.x;
  for (int c = t; c < IC; c += 256) { w1s[c] = w1[c]; w2s[c] = w2[c]; }
  __syncthreads();
  const int wave = t >> 6, lane = t & 63;
  const int i = blockIdx.x * 4 + wave;
  if (i >= NN) return;
  const float* Xi = X + (size_t)i * IC;
  double s1 = 0.0, s2 = 0.0;
  for (int c = lane; c < IC; c += 64) {
    double x = (double)Xi[c];
    s1 = fma(x, w1s[c], s1);
    s2 = fma(x, w2s[c], s2);
  }
  for (int o = 32; o; o >>= 1) { s1 += __shfl_down(s1, o, 64); s2 += __shfl_down(s2, o, 64); }
  if (lane == 0) { k1[i] = s1; k2[i] = s2; }
}

// ---------------- K partials: Kp[split] = X @ W^T over k-chunk (fp32) ----------------
__global__ __launch_bounds__(256) void gemmK(const float* __restrict__ X, const float* __restrict__ W,
                                             float* __restrict__ Kp, int chunk) {
  __shared__ float Xs[32][33];
  __shared__ float Ws[32][132];
  const int t  = threadIdx.x;
  const int rb = blockIdx.x * 32;
  const int ks = blockIdx.y * chunk;
  const int ke = min(IC, ks + chunk);
  float* __restrict__ Ko = Kp + (size_t)blockIdx.y * NNOC;
  const int row0 = (t >> 5) * 4;
  const int col4 = (t & 31) * 4;
  float acc[4][4];
#pragma unroll
  for (int r = 0; r < 4; r++)
#pragma unroll
    for (int c = 0; c < 4; c++) acc[r][c] = 0.f;

  for (int kb = ks; kb < ke; kb += 32) {
#pragma unroll
    for (int it = 0; it < 4; it++) {
      int idx = t + it * 256;
      int r = idx >> 5, c = idx & 31;
      int gr = rb + r, gc = kb + c;
      Xs[r][c] = (gr < NN && gc < ke) ? X[(size_t)gr * IC + gc] : 0.f;
    }
#pragma unroll
    for (int it = 0; it < 16; it++) {
      int idx = t + it * 256;
      int o = idx >> 5, c = idx & 31;
      int gc = kb + c;
      Ws[c][o] = (gc < ke) ? W[(size_t)o * IC + gc] : 0.f;
    }
    __syncthreads();
#pragma unroll
    for (int kk = 0; kk < 32; kk++) {
      const float4 w4 = *reinterpret_cast<const float4*>(&Ws[kk][col4]);
      float x0 = Xs[row0 + 0][kk];
      float x1 = Xs[row0 + 1][kk];
      float x2 = Xs[row0 + 2][kk];
      float x3 = Xs[row0 + 3][kk];
      acc[0][0] = fmaf(x0, w4.x, acc[0][0]); acc[0][1] = fmaf(x0, w4.y, acc[0][1]);
      acc[0][2] = fmaf(x0, w4.z, acc[0][2]); acc[0][3] = fmaf(x0, w4.w, acc[0][3]);
      acc[1][0] = fmaf(x1, w4.x, acc[1][0]); acc[1][1] = fmaf(x1, w4.y, acc[1][1]);
      acc[1][2] = fmaf(x1, w4.z, acc[1][2]); acc[1][3] = fmaf(x1, w4.w, acc[1][3]);
      acc[2][0] = fmaf(x2, w4.x, acc[2][0]); acc[2][1] = fmaf(x2, w4.y, acc[2][1]);
      acc[2][2] = fmaf(x2, w4.z, acc[2][2]); acc[2][3] = fmaf(x2, w4.w, acc[2][3]);
      acc[3][0] = fmaf(x3, w4.x, acc[3][0]); acc[3][1] = fmaf(x3, w4.y, acc[3][1]);
      acc[3][2] = fmaf(x3, w4.z, acc[3][2]); acc[3][3] = fmaf(x3, w4.w, acc[3][3]);
    }
    __syncthreads();
  }
#pragma unroll
  for (int r = 0; r < 4; r++) {
    int gr = rb + row0 + r;
    if (gr < NN) {
      float4 v = make_float4(acc[r][0], acc[r][1], acc[r][2], acc[r][3]);
      *reinterpret_cast<float4*>(&Ko[(size_t)gr * OC + col4]) = v;
    }
  }
}

// ---------------- merge split-K partials ----------------
__global__ __launch_bounds__(256) void mergeK(const float* __restrict__ Kp, float* __restrict__ Kf) {
  size_t i = (size_t)blockIdx.x * 256 + threadIdx.x;
  if (i < NNOC) Kf[i] = Kp[i] + Kp[NNOC + i];
}

// ---------------- u1 = U^T@k1, s = U^T@1 (fp64, float4 cols) ----------------
__global__ __launch_bounds__(256) void ut_reduce(const float4* __restrict__ U4, const double* __restrict__ k1,
                                                 double* __restrict__ u1, double* __restrict__ s) {
  int c4 = blockIdx.x * 256 + threadIdx.x;
  if (c4 >= NV) return;
  int r0 = blockIdx.y * 32;
  int r1 = min(NN, r0 + 32);
  double au0 = 0, au1_ = 0, au2 = 0, au3 = 0, as0 = 0, as1 = 0, as2 = 0, as3 = 0;
  for (int r = r0; r < r1; r++) {
    float4 u = U4[(size_t)r * NV + c4];
    double kr = k1[r];
    au0 = fma((double)u.x, kr, au0); au1_ = fma((double)u.y, kr, au1_);
    au2 = fma((double)u.z, kr, au2); au3 = fma((double)u.w, kr, au3);
    as0 += (double)u.x; as1 += (double)u.y; as2 += (double)u.z; as3 += (double)u.w;
  }
  int c = c4 * 4;
  atomicAdd(&u1[c + 0], au0); atomicAdd(&u1[c + 1], au1_);
  atomicAdd(&u1[c + 2], au2); atomicAdd(&u1[c + 3], au3);
  atomicAdd(&s[c + 0], as0);  atomicAdd(&s[c + 1], as1);
  atomicAdd(&s[c + 2], as2);  atomicAdd(&s[c + 3], as3);
}

// ---------------- p = U@(lmbd*u1), q = U@(lmbd*s) (fp64), one wave per row ----------------
__global__ __launch_bounds__(256) void uv_kernel(const float4* __restrict__ U4, const float4* __restrict__ L4,
                                                 const double2* __restrict__ u1d, const double2* __restrict__ sd,
                                                 double* __restrict__ p, double* __restrict__ q) {
  const int t = threadIdx.x;
  const int wave = t >> 6, lane = t & 63;
  const int r = blockIdx.x * 4 + wave;
  if (r >= NN) return;
  const float4* Ur = U4 + (size_t)r * NV;
  double ap = 0.0, aq = 0.0;
  for (int c4 = lane; c4 < NV; c4 += 64) {
    float4 u = Ur[c4];
    float4 lm = L4[c4];
    double2 ua = u1d[c4 * 2], ub = u1d[c4 * 2 + 1];
    double2 sa = sd[c4 * 2],  sb = sd[c4 * 2 + 1];
    ap = fma((double)u.x, (double)lm.x * ua.x, ap);
    ap = fma((double)u.y, (double)lm.y * ua.y, ap);
    ap = fma((double)u.z, (double)lm.z * ub.x, ap);
    ap = fma((double)u.w, (double)lm.w * ub.y, ap);
    aq = fma((double)u.x, (double)lm.x * sa.x, aq);
    aq = fma((double)u.y, (double)lm.y * sa.y, aq);
    aq = fma((double)u.z, (double)lm.z * sb.x, aq);
    aq = fma((double)u.w, (double)lm.w * sb.y, aq);
  }
  for (int o = 32; o; o >>= 1) { ap += __shfl_down(ap, o, 64); aq += __shfl_down(aq, o, 64); }
  if (lane == 0) { p[r] = ap; q[r] = aq; }
}

// ---------------- sort pipeline ----------------
__global__ __launch_bounds__(256) void minmax_k2(const double* __restrict__ k2d, double* __restrict__ hdr) {
  __shared__ double smn[4], smx[4];
  int t = threadIdx.x, wv = t >> 6, ln = t & 63;
  double mn = 1e300, mx = -1e300;
  for (int j = t; j < NN; j += 256) { double v = k2d[j]; mn = fmin(mn, v); mx = fmax(mx, v); }
  for (int o = 32; o; o >>= 1) { mn = fmin(mn, __shfl_xor(mn, o, 64)); mx = fmax(mx, __shfl_xor(mx, o, 64)); }
  if (ln == 0) { smn[wv] = mn; smx[wv] = mx; }
  __syncthreads();
  if (t == 0) {
    hdr[0] = fmin(fmin(smn[0], smn[1]), fmin(smn[2], smn[3]));
    hdr[1] = fmax(fmax(smx[0], smx[1]), fmax(smx[2], smx[3]));
  }
}

__device__ __forceinline__ int bucket_of(double v, double minv, double scale) {
  int b = (int)((v - minv) * scale);
  return min(NB - 1, max(0, b));
}

__global__ __launch_bounds__(256) void hist_k2(const double* __restrict__ k2d, const double* __restrict__ hdr,
                                               int* __restrict__ hist) {
  int j = blockIdx.x * 256 + threadIdx.x;
  if (j >= NN) return;
  double minv = hdr[0];
  double scale = NB / fmax(hdr[1] - minv, 1e-30);
  atomicAdd(&hist[bucket_of(k2d[j], minv, scale)], 1);
}

__global__ __launch_bounds__(1024) void scan_hist(const int* __restrict__ hist, int* __restrict__ off) {
  __shared__ int ps[1024];
  int t = threadIdx.x;
  int4 v = ((const int4*)hist)[t];
  int s = v.x + v.y + v.z + v.w;
  ps[t] = s;
  __syncthreads();
  for (int d = 1; d < 1024; d <<= 1) {
    int x = (t >= d) ? ps[t - d] : 0;
    __syncthreads();
    ps[t] += x;
    __syncthreads();
  }
  int excl = ps[t] - s;
  int4 o;
  o.x = excl; o.y = excl + v.x; o.z = o.y + v.y; o.w = o.z + v.z;
  ((int4*)off)[t] = o;
}

__global__ __launch_bounds__(256) void scatter_k2(const double* __restrict__ k2d, const double* __restrict__ hdr,
                                                  int* __restrict__ off, int* __restrict__ sortedj,
                                                  double* __restrict__ kvd) {
  int j = blockIdx.x * 256 + threadIdx.x;
  if (j >= NN) return;
  double minv = hdr[0];
  double scale = NB / fmax(hdr[1] - minv, 1e-30);
  int pos = atomicAdd(&off[bucket_of(k2d[j], minv, scale)], 1);
  sortedj[pos] = j;
  kvd[pos] = k2d[j];
}

// ---------------- softmax+H: sorted-tail walk, ONE BLOCK (4 waves) per row ----------------
// Walk 256 positions/round, cross-wave ballot compaction; tight termination bounds;
// gather parallel over 4 candidate-groups x 64 channels (2 ch/thread) with 2x unroll.
__global__ __launch_bounds__(256) void softmaxH(const int* __restrict__ A,
                                                const double* __restrict__ p, const double* __restrict__ q,
                                                const double* __restrict__ kvd, const int* __restrict__ sortedj,
                                                const double* __restrict__ hdr,
                                                const float* __restrict__ K, float* __restrict__ H) {
  __shared__ float vf[NN];          // 10.8 KB: candidate v, then w
  __shared__ short js[NN];          //  5.4 KB: candidate j
  __shared__ float hpart[4][128];   //  2.0 KB
  __shared__ int wcnt[4];
  __shared__ double wfv[4], wbnd[4];
  __shared__ float redf[4];

  const int i = blockIdx.x;
  const int t = threadIdx.x;
  const int wv = t >> 6, lane = t & 63;
  const double pi = p[i], qi = q[i];
  const double bw = (hdr[1] - hdr[0]) * (1.0 / NB);
  const double margin = 36.0 + 2.0 * fabs(qi) * bw;   // bucket-jitter covered
  const int* Arow = A + (size_t)i * NN;
  const bool sgn = (qi >= 0.0);
  const unsigned long long ltmask = (1ull << lane) - 1ull;
  int nlist = 0;
  double m_lb = -1e300;

  // WALK A: descending v = pi + qi*k2. Remaining positions' v <= round-min (+jitter).
  int coveredA = 0;
  for (int r = 0; r * 256 < NN; r++) {
    int idx = r * 256 + t;
    bool ok = idx < NN;
    double v = 0.0; int j = 0; int a = 0;
    if (ok) {
      int pos = sgn ? (NN - 1 - idx) : idx;
      v = fma(qi, kvd[pos], pi);
      j = sortedj[pos];
      a = Arow[j];
    }
    bool isn = ok && (a != 0);
    unsigned long long mask = __ballot(isn);
    int wo = __popcll(mask & ltmask);
    double fv = isn ? fabs(v) : -1e300;
    double bnd = ok ? v : 1e300;      // round-min over ok lanes bounds the remainder
    for (int o = 32; o; o >>= 1) {
      fv = fmax(fv, __shfl_xor(fv, o, 64));
      bnd = fmin(bnd, __shfl_xor(bnd, o, 64));
    }
    if (lane == 0) { wcnt[wv] = __popcll(mask); wfv[wv] = fv; wbnd[wv] = bnd; }
    __syncthreads();
    int c0 = wcnt[0], c1 = wcnt[1], c2 = wcnt[2], c3 = wcnt[3];
    int base = nlist + (wv > 0 ? c0 : 0) + (wv > 1 ? c1 : 0) + (wv > 2 ? c2 : 0);
    if (isn) { js[base + wo] = (short)j; vf[base + wo] = (float)v; }
    nlist += c0 + c1 + c2 + c3;
    m_lb = fmax(m_lb, fmax(fmax(wfv[0], wfv[1]), fmax(wfv[2], wfv[3])));
    double rbnd = fmin(fmin(wbnd[0], wbnd[1]), fmin(wbnd[2], wbnd[3]));
    __syncthreads();
    coveredA = min(NN, (r + 1) * 256);
    if (rbnd < m_lb - margin) break;
  }
  const int remB = NN - coveredA;

  // WALK B: ascending v; remaining e = -v <= -(round-max) (+jitter).
  for (int r = 0; r * 256 < remB; r++) {
    int idx = r * 256 + t;
    bool ok = idx < remB;
    double v = 0.0; int j = 0; int a = 0;
    if (ok) {
      int pos = sgn ? idx : (NN - 1 - idx);
      v = fma(qi, kvd[pos], pi);
      j = sortedj[pos];
      a = Arow[j];
    }
    bool isn = ok && (a != 0);
    unsigned long long mask = __ballot(isn);
    int wo = __popcll(mask & ltmask);
    double fv = isn ? fabs(v) : -1e300;
    double bnd = ok ? v : -1e300;     // round-max over ok lanes
    for (int o = 32; o; o >>= 1) {
      fv = fmax(fv, __shfl_xor(fv, o, 64));
      bnd = fmax(bnd, __shfl_xor(bnd, o, 64));
    }
    if (lane == 0) { wcnt[wv] = __popcll(mask); wfv[wv] = fv; wbnd[wv] = bnd; }
    __syncthreads();
    int c0 = wcnt[0], c1 = wcnt[1], c2 = wcnt[2], c3 = wcnt[3];
    int base = nlist + (wv > 0 ? c0 : 0) + (wv > 1 ? c1 : 0) + (wv > 2 ? c2 : 0);
    if (isn) { js[base + wo] = (short)j; vf[base + wo] = (float)v; }
    nlist += c0 + c1 + c2 + c3;
    m_lb = fmax(m_lb, fmax(fmax(wfv[0], wfv[1]), fmax(wfv[2], wfv[3])));
    double rbnd = fmax(fmax(wbnd[0], wbnd[1]), fmax(wbnd[2], wbnd[3]));
    __syncthreads();
    if (-rbnd < m_lb - margin) break;
  }

  // weights (m_lb is the exact masked max: its argmax was walked & is a neighbor)
  const float fm = (float)m_lb;
  float sw = 0.f;
  for (int c = t; c < nlist; c += 256) {
    float w = __expf(fabsf(vf[c]) - fm);
    vf[c] = w;
    sw += w;
  }
  for (int o = 32; o; o >>= 1) sw += __shfl_xor(sw, o, 64);
  if (lane == 0) redf[wv] = sw;
  __syncthreads();
  const float sumw = (redf[0] + redf[1]) + (redf[2] + redf[3]);

  // gather: H[i] = sum_c w_c K[j_c] / sumw ; 4 candidate groups, 64 ch x 2 per thread
  const int ch = t & 63, g = t >> 6;
  float a0 = 0.f, a1 = 0.f;
  int c = g;
  for (; c + 4 < nlist; c += 8) {
    float w0 = vf[c], w1 = vf[c + 4];
    const float* K0 = K + (size_t)js[c] * OC;
    const float* K1 = K + (size_t)js[c + 4] * OC;
    float k00 = K0[ch], k01 = K0[64 + ch];
    float k10 = K1[ch], k11 = K1[64 + ch];
    a0 = fmaf(w0, k00, a0); a1 = fmaf(w0, k01, a1);
    a0 = fmaf(w1, k10, a0); a1 = fmaf(w1, k11, a1);
  }
  for (; c < nlist; c += 4) {
    float w = vf[c];
    const float* Kr = K + (size_t)js[c] * OC;
    a0 = fmaf(w, Kr[ch], a0);
    a1 = fmaf(w, Kr[64 + ch], a1);
  }
  hpart[g][ch] = a0;
  hpart[g][64 + ch] = a1;
  __syncthreads();
  if (t < 128) {
    float hv = (hpart[0][t] + hpart[1][t]) + (hpart[2][t] + hpart[3][t]);
    H[(size_t)i * OC + t] = hv / sumw;
  }
}

extern "C" void kernel_launch(void* const* d_in, const int* in_sizes, int n_in,
                              void* d_out, int out_size, void* d_ws, size_t ws_size,
                              hipStream_t stream) {
  const float* X    = (const float*)d_in[0];
  const int*   A    = (const int*)d_in[1];
  const float* U    = (const float*)d_in[2];
  const float* W    = (const float*)d_in[3];
  const float* a1   = (const float*)d_in[4];
  const float* a2   = (const float*)d_in[5];
  const float* lmbd = (const float*)d_in[6];
  float* H = (float*)d_out;

  const size_t aux_bytes = (size_t)(7 * NN + 2 * IC + 2) * 8 + (size_t)(2 * NB + NN) * 4;
  char* base = (char*)d_ws;
  int nsplit;
  float *Kp, *Kf;
  size_t koff;
  if (ws_size >= 3 * NNOC * 4 + aux_bytes) {
    nsplit = 2;
    Kp = (float*)base;
    Kf = (float*)(base + 2 * NNOC * 4);
    koff = 3 * NNOC * 4;
  } else {
    nsplit = 1;
    Kp = Kf = (float*)base;
    koff = NNOC * 4;
  }
  double* dbl = (double*)(base + koff);
  double* k1  = dbl;            // NN
  double* k2  = k1 + NN;        // NN
  double* u1  = k2 + NN;        // NN
  double* sC  = u1 + NN;        // NN
  double* p   = sC + NN;        // NN
  double* q   = p  + NN;        // NN
  double* kvd = q  + NN;        // NN
  double* w1  = kvd + NN;       // IC
  double* w2  = w1 + IC;        // IC
  double* hdr = w2 + IC;        // 2
  int* hist    = (int*)(hdr + 2);  // NB
  int* offb    = hist + NB;        // NB
  int* sortedj = offb + NB;        // NN

  const int chunk = (IC + nsplit - 1) / nsplit;

  zero_ws2<<<(2 * NN + 255) / 256, 256, 0, stream>>>(u1, 2 * NN, hist, NB);
  wvec<<<(IC + 255) / 256, 256, 0, stream>>>(W, a1, a2, w1, w2);
  xw<<<NN / 4, 256, 0, stream>>>(X, w1, w2, k1, k2);
  gemmK<<<dim3((NN + 31) / 32, nsplit), 256, 0, stream>>>(X, W, Kp, chunk);
  if (nsplit == 2)
    mergeK<<<(int)((NNOC + 255) / 256), 256, 0, stream>>>(Kp, Kf);
  ut_reduce<<<dim3((NV + 255) / 256, (NN + 31) / 32), 256, 0, stream>>>((const float4*)U, k1, u1, sC);
  uv_kernel<<<NN / 4, 256, 0, stream>>>((const float4*)U, (const float4*)lmbd,
                                        (const double2*)u1, (const double2*)sC, p, q);
  minmax_k2<<<1, 256, 0, stream>>>(k2, hdr);
  hist_k2<<<(NN + 255) / 256, 256, 0, stream>>>(k2, hdr, hist);
  scan_hist<<<1, 1024, 0, stream>>>(hist, offb);
  scatter_k2<<<(NN + 255) / 256, 256, 0, stream>>>(k2, hdr, offb, sortedj, kvd);
  softmaxH<<<NN, 256, 0, stream>>>(A, p, q, kvd, sortedj, hdr, Kf, H);
}

// Round 8
// 285.416 us; speedup vs baseline: 3.3605x; 1.2550x over previous
//
#include <hip/hip_runtime.h>
#include <math.h>

#define NN 2708
#define IC 1433
#define OC 128
#define NV (NN / 4)          // 677 float4/int4 per row (exact)
#define NNOC ((size_t)NN * OC)
#define NB 4096              // sort buckets

// ---------------- zero fp64 targets + int histogram in one launch ----------------
__global__ __launch_bounds__(256) void zero_ws2(double* d, int nd, int* hi, int nh) {
  int i = blockIdx.x * 256 + threadIdx.x;
  if (i < nd) d[i] = 0.0;
  if (i < nh) hi[i] = 0;
}

// ---------------- w1 = W^T a1, w2 = W^T a2 (fp64) ----------------
__global__ __launch_bounds__(256) void wvec(const float* __restrict__ W, const float* __restrict__ a1,
                                            const float* __restrict__ a2,
                                            double* __restrict__ w1, double* __restrict__ w2) {
  int c = blockIdx.x * 256 + threadIdx.x;
  if (c >= IC) return;
  double s1 = 0.0, s2 = 0.0;
  for (int o = 0; o < OC; o++) {
    double w = (double)W[(size_t)o * IC + c];
    s1 = fma(w, (double)a1[o], s1);
    s2 = fma(w, (double)a2[o], s2);
  }
  w1[c] = s1; w2[c] = s2;
}

// ---------------- k1 = X@w1, k2 = X@w2 (fp64), one wave per row ----------------
__global__ __launch_bounds__(256) void xw(const float* __restrict__ X, const double* __restrict__ w1,
                                          const double* __restrict__ w2,
                                          double* __restrict__ k1, double* __restrict__ k2) {
  __shared__ double w1s[IC];
  __shared__ double w2s[IC];
  const int t = threadIdx.x;
  for (int c = t; c < IC; c += 256) { w1s[c] = w1[c]; w2s[c] = w2[c]; }
  __syncthreads();
  const int wave = t >> 6, lane = t & 63;
  const int i = blockIdx.x * 4 + wave;
  if (i >= NN) return;
  const float* Xi = X + (size_t)i * IC;
  double s1 = 0.0, s2 = 0.0;
  for (int c = lane; c < IC; c += 64) {
    double x = (double)Xi[c];
    s1 = fma(x, w1s[c], s1);
    s2 = fma(x, w2s[c], s2);
  }
  for (int o = 32; o; o >>= 1) { s1 += __shfl_down(s1, o, 64); s2 += __shfl_down(s2, o, 64); }
  if (lane == 0) { k1[i] = s1; k2[i] = s2; }
}

// ---------------- Wt[k][o] = W[o][k] (32x32 LDS tile transpose) ----------------
__global__ __launch_bounds__(256) void transposeW(const float* __restrict__ W, float* __restrict__ Wt) {
  __shared__ float tile[32][33];
  const int t = threadIdx.x;
  const int k0 = blockIdx.x * 32, o0 = blockIdx.y * 32;
#pragma unroll
  for (int it = 0; it < 4; it++) {
    int ro = (t >> 5) + it * 8;
    int k  = k0 + (t & 31);
    tile[ro][t & 31] = (k < IC) ? W[(size_t)(o0 + ro) * IC + k] : 0.f;  // coalesced along k
  }
  __syncthreads();
#pragma unroll
  for (int it = 0; it < 4; it++) {
    int rk = (t >> 5) + it * 8;
    int k  = k0 + rk;
    if (k < IC) Wt[(size_t)k * OC + o0 + (t & 31)] = tile[t & 31][rk];  // coalesced along o
  }
}

// ---------------- K partials: Kp[split] = X @ Wt over k-chunk (fp32, conflict-free LDS) ----------------
__global__ __launch_bounds__(256) void gemmK(const float* __restrict__ X, const float* __restrict__ Wt,
                                             float* __restrict__ Kp, int chunk) {
  __shared__ float Xs[32][36];    // [row][k], pad to 36: float4-aligned k-reads, lane-consecutive writes
  __shared__ float Ws[32][132];   // [k][col], lane-consecutive float4 writes, data-floor reads
  const int t  = threadIdx.x;
  const int rb = blockIdx.x * 32;
  const int ks = blockIdx.y * chunk;
  const int ke = min(IC, ks + chunk);
  float* __restrict__ Ko = Kp + (size_t)blockIdx.y * NNOC;
  const int row0 = (t >> 5) * 4;
  const int col4 = (t & 31) * 4;
  float acc[4][4];
#pragma unroll
  for (int r = 0; r < 4; r++)
#pragma unroll
    for (int c = 0; c < 4; c++) acc[r][c] = 0.f;

  for (int kb = ks; kb < ke; kb += 32) {
#pragma unroll
    for (int it = 0; it < 4; it++) {          // X tile 32x32, scalar (X rows 4B-aligned only)
      int idx = t + it * 256;
      int r = idx >> 5, c = idx & 31;
      int gr = rb + r, gc = kb + c;
      Xs[r][c] = (gr < NN && gc < ke) ? X[(size_t)gr * IC + gc] : 0.f;
    }
#pragma unroll
    for (int it = 0; it < 4; it++) {          // W tile 32k x 128col, float4 both sides
      int idx4 = t + it * 256;
      int k = idx4 >> 5, cg = (idx4 & 31) * 4;
      int gk = kb + k;
      float4 v = make_float4(0.f, 0.f, 0.f, 0.f);
      if (gk < ke) v = *reinterpret_cast<const float4*>(&Wt[(size_t)gk * OC + cg]);
      *reinterpret_cast<float4*>(&Ws[k][cg]) = v;
    }
    __syncthreads();
#pragma unroll
    for (int g = 0; g < 8; g++) {
      float xr[4][4];
#pragma unroll
      for (int r = 0; r < 4; r++)
        *reinterpret_cast<float4*>(xr[r]) = *reinterpret_cast<const float4*>(&Xs[row0 + r][g * 4]);
#pragma unroll
      for (int j = 0; j < 4; j++) {
        const float4 w4 = *reinterpret_cast<const float4*>(&Ws[g * 4 + j][col4]);
#pragma unroll
        for (int r = 0; r < 4; r++) {
          acc[r][0] = fmaf(xr[r][j], w4.x, acc[r][0]);
          acc[r][1] = fmaf(xr[r][j], w4.y, acc[r][1]);
          acc[r][2] = fmaf(xr[r][j], w4.z, acc[r][2]);
          acc[r][3] = fmaf(xr[r][j], w4.w, acc[r][3]);
        }
      }
    }
    __syncthreads();
  }
#pragma unroll
  for (int r = 0; r < 4; r++) {
    int gr = rb + row0 + r;
    if (gr < NN) {
      float4 v = make_float4(acc[r][0], acc[r][1], acc[r][2], acc[r][3]);
      *reinterpret_cast<float4*>(&Ko[(size_t)gr * OC + col4]) = v;
    }
  }
}

// ---------------- merge split-K partials (float4, nsplit-generic) ----------------
__global__ __launch_bounds__(256) void mergeK(const float4* __restrict__ Kp, float4* __restrict__ Kf, int nsplit) {
  size_t i = (size_t)blockIdx.x * 256 + threadIdx.x;
  const size_t n4 = NNOC / 4;
  if (i >= n4) return;
  float4 s = Kp[i];
  for (int ps = 1; ps < nsplit; ps++) {
    float4 v = Kp[(size_t)ps * n4 + i];
    s.x += v.x; s.y += v.y; s.z += v.z; s.w += v.w;
  }
  Kf[i] = s;
}

// ---------------- u1 = U^T@k1, s = U^T@1 (fp64, float4 cols) ----------------
__global__ __launch_bounds__(256) void ut_reduce(const float4* __restrict__ U4, const double* __restrict__ k1,
                                                 double* __restrict__ u1, double* __restrict__ s) {
  int c4 = blockIdx.x * 256 + threadIdx.x;
  if (c4 >= NV) return;
  int r0 = blockIdx.y * 32;
  int r1 = min(NN, r0 + 32);
  double au0 = 0, au1_ = 0, au2 = 0, au3 = 0, as0 = 0, as1 = 0, as2 = 0, as3 = 0;
  for (int r = r0; r < r1; r++) {
    float4 u = U4[(size_t)r * NV + c4];
    double kr = k1[r];
    au0 = fma((double)u.x, kr, au0); au1_ = fma((double)u.y, kr, au1_);
    au2 = fma((double)u.z, kr, au2); au3 = fma((double)u.w, kr, au3);
    as0 += (double)u.x; as1 += (double)u.y; as2 += (double)u.z; as3 += (double)u.w;
  }
  int c = c4 * 4;
  atomicAdd(&u1[c + 0], au0); atomicAdd(&u1[c + 1], au1_);
  atomicAdd(&u1[c + 2], au2); atomicAdd(&u1[c + 3], au3);
  atomicAdd(&s[c + 0], as0);  atomicAdd(&s[c + 1], as1);
  atomicAdd(&s[c + 2], as2);  atomicAdd(&s[c + 3], as3);
}

// ---------------- p = U@(lmbd*u1), q = U@(lmbd*s) (fp64), one wave per row ----------------
__global__ __launch_bounds__(256) void uv_kernel(const float4* __restrict__ U4, const float4* __restrict__ L4,
                                                 const double2* __restrict__ u1d, const double2* __restrict__ sd,
                                                 double* __restrict__ p, double* __restrict__ q) {
  const int t = threadIdx.x;
  const int wave = t >> 6, lane = t & 63;
  const int r = blockIdx.x * 4 + wave;
  if (r >= NN) return;
  const float4* Ur = U4 + (size_t)r * NV;
  double ap = 0.0, aq = 0.0;
  for (int c4 = lane; c4 < NV; c4 += 64) {
    float4 u = Ur[c4];
    float4 lm = L4[c4];
    double2 ua = u1d[c4 * 2], ub = u1d[c4 * 2 + 1];
    double2 sa = sd[c4 * 2],  sb = sd[c4 * 2 + 1];
    ap = fma((double)u.x, (double)lm.x * ua.x, ap);
    ap = fma((double)u.y, (double)lm.y * ua.y, ap);
    ap = fma((double)u.z, (double)lm.z * ub.x, ap);
    ap = fma((double)u.w, (double)lm.w * ub.y, ap);
    aq = fma((double)u.x, (double)lm.x * sa.x, aq);
    aq = fma((double)u.y, (double)lm.y * sa.y, aq);
    aq = fma((double)u.z, (double)lm.z * sb.x, aq);
    aq = fma((double)u.w, (double)lm.w * sb.y, aq);
  }
  for (int o = 32; o; o >>= 1) { ap += __shfl_down(ap, o, 64); aq += __shfl_down(aq, o, 64); }
  if (lane == 0) { p[r] = ap; q[r] = aq; }
}

// ---------------- sort pipeline ----------------
__global__ __launch_bounds__(256) void minmax_k2(const double* __restrict__ k2d, double* __restrict__ hdr) {
  __shared__ double smn[4], smx[4];
  int t = threadIdx.x, wv = t >> 6, ln = t & 63;
  double mn = 1e300, mx = -1e300;
  for (int j = t; j < NN; j += 256) { double v = k2d[j]; mn = fmin(mn, v); mx = fmax(mx, v); }
  for (int o = 32; o; o >>= 1) { mn = fmin(mn, __shfl_xor(mn, o, 64)); mx = fmax(mx, __shfl_xor(mx, o, 64)); }
  if (ln == 0) { smn[wv] = mn; smx[wv] = mx; }
  __syncthreads();
  if (t == 0) {
    hdr[0] = fmin(fmin(smn[0], smn[1]), fmin(smn[2], smn[3]));
    hdr[1] = fmax(fmax(smx[0], smx[1]), fmax(smx[2], smx[3]));
  }
}

__device__ __forceinline__ int bucket_of(double v, double minv, double scale) {
  int b = (int)((v - minv) * scale);
  return min(NB - 1, max(0, b));
}

__global__ __launch_bounds__(256) void hist_k2(const double* __restrict__ k2d, const double* __restrict__ hdr,
                                               int* __restrict__ hist) {
  int j = blockIdx.x * 256 + threadIdx.x;
  if (j >= NN) return;
  double minv = hdr[0];
  double scale = NB / fmax(hdr[1] - minv, 1e-30);
  atomicAdd(&hist[bucket_of(k2d[j], minv, scale)], 1);
}

__global__ __launch_bounds__(1024) void scan_hist(const int* __restrict__ hist, int* __restrict__ off) {
  __shared__ int ps[1024];
  int t = threadIdx.x;
  int4 v = ((const int4*)hist)[t];
  int s = v.x + v.y + v.z + v.w;
  ps[t] = s;
  __syncthreads();
  for (int d = 1; d < 1024; d <<= 1) {
    int x = (t >= d) ? ps[t - d] : 0;
    __syncthreads();
    ps[t] += x;
    __syncthreads();
  }
  int excl = ps[t] - s;
  int4 o;
  o.x = excl; o.y = excl + v.x; o.z = o.y + v.y; o.w = o.z + v.z;
  ((int4*)off)[t] = o;
}

__global__ __launch_bounds__(256) void scatter_k2(const double* __restrict__ k2d, const double* __restrict__ hdr,
                                                  int* __restrict__ off, int* __restrict__ sortedj,
                                                  double* __restrict__ kvd) {
  int j = blockIdx.x * 256 + threadIdx.x;
  if (j >= NN) return;
  double minv = hdr[0];
  double scale = NB / fmax(hdr[1] - minv, 1e-30);
  int pos = atomicAdd(&off[bucket_of(k2d[j], minv, scale)], 1);
  sortedj[pos] = j;
  kvd[pos] = k2d[j];
}

// ---------------- softmax+H: sorted-tail walk, one block per row ----------------
__global__ __launch_bounds__(256) void softmaxH(const int* __restrict__ A,
                                                const double* __restrict__ p, const double* __restrict__ q,
                                                const double* __restrict__ kvd, const int* __restrict__ sortedj,
                                                const double* __restrict__ hdr,
                                                const float* __restrict__ K, float* __restrict__ H) {
  __shared__ float vf[NN];
  __shared__ short js[NN];
  __shared__ float hpart[4][128];
  __shared__ int wcnt[4];
  __shared__ double wfv[4], wbnd[4];
  __shared__ float redf[4];

  const int i = blockIdx.x;
  const int t = threadIdx.x;
  const int wv = t >> 6, lane = t & 63;
  const double pi = p[i], qi = q[i];
  const double bw = (hdr[1] - hdr[0]) * (1.0 / NB);
  const double margin = 36.0 + 2.0 * fabs(qi) * bw;
  const int* Arow = A + (size_t)i * NN;
  const bool sgn = (qi >= 0.0);
  const unsigned long long ltmask = (1ull << lane) - 1ull;
  int nlist = 0;
  double m_lb = -1e300;

  int coveredA = 0;
  for (int r = 0; r * 256 < NN; r++) {
    int idx = r * 256 + t;
    bool ok = idx < NN;
    double v = 0.0; int j = 0; int a = 0;
    if (ok) {
      int pos = sgn ? (NN - 1 - idx) : idx;
      v = fma(qi, kvd[pos], pi);
      j = sortedj[pos];
      a = Arow[j];
    }
    bool isn = ok && (a != 0);
    unsigned long long mask = __ballot(isn);
    int wo = __popcll(mask & ltmask);
    double fv = isn ? fabs(v) : -1e300;
    double bnd = ok ? v : 1e300;
    for (int o = 32; o; o >>= 1) {
      fv = fmax(fv, __shfl_xor(fv, o, 64));
      bnd = fmin(bnd, __shfl_xor(bnd, o, 64));
    }
    if (lane == 0) { wcnt[wv] = __popcll(mask); wfv[wv] = fv; wbnd[wv] = bnd; }
    __syncthreads();
    int c0 = wcnt[0], c1 = wcnt[1], c2 = wcnt[2], c3 = wcnt[3];
    int base = nlist + (wv > 0 ? c0 : 0) + (wv > 1 ? c1 : 0) + (wv > 2 ? c2 : 0);
    if (isn) { js[base + wo] = (short)j; vf[base + wo] = (float)v; }
    nlist += c0 + c1 + c2 + c3;
    m_lb = fmax(m_lb, fmax(fmax(wfv[0], wfv[1]), fmax(wfv[2], wfv[3])));
    double rbnd = fmin(fmin(wbnd[0], wbnd[1]), fmin(wbnd[2], wbnd[3]));
    __syncthreads();
    coveredA = min(NN, (r + 1) * 256);
    if (rbnd < m_lb - margin) break;
  }
  const int remB = NN - coveredA;

  for (int r = 0; r * 256 < remB; r++) {
    int idx = r * 256 + t;
    bool ok = idx < remB;
    double v = 0.0; int j = 0; int a = 0;
    if (ok) {
      int pos = sgn ? idx : (NN - 1 - idx);
      v = fma(qi, kvd[pos], pi);
      j = sortedj[pos];
      a = Arow[j];
    }
    bool isn = ok && (a != 0);
    unsigned long long mask = __ballot(isn);
    int wo = __popcll(mask & ltmask);
    double fv = isn ? fabs(v) : -1e300;
    double bnd = ok ? v : -1e300;
    for (int o = 32; o; o >>= 1) {
      fv = fmax(fv, __shfl_xor(fv, o, 64));
      bnd = fmax(bnd, __shfl_xor(bnd, o, 64));
    }
    if (lane == 0) { wcnt[wv] = __popcll(mask); wfv[wv] = fv; wbnd[wv] = bnd; }
    __syncthreads();
    int c0 = wcnt[0], c1 = wcnt[1], c2 = wcnt[2], c3 = wcnt[3];
    int base = nlist + (wv > 0 ? c0 : 0) + (wv > 1 ? c1 : 0) + (wv > 2 ? c2 : 0);
    if (isn) { js[base + wo] = (short)j; vf[base + wo] = (float)v; }
    nlist += c0 + c1 + c2 + c3;
    m_lb = fmax(m_lb, fmax(fmax(wfv[0], wfv[1]), fmax(wfv[2], wfv[3])));
    double rbnd = fmax(fmax(wbnd[0], wbnd[1]), fmax(wbnd[2], wbnd[3]));
    __syncthreads();
    if (-rbnd < m_lb - margin) break;
  }

  const float fm = (float)m_lb;
  float sw = 0.f;
  for (int c = t; c < nlist; c += 256) {
    float w = __expf(fabsf(vf[c]) - fm);
    vf[c] = w;
    sw += w;
  }
  for (int o = 32; o; o >>= 1) sw += __shfl_xor(sw, o, 64);
  if (lane == 0) redf[wv] = sw;
  __syncthreads();
  const float sumw = (redf[0] + redf[1]) + (redf[2] + redf[3]);

  const int ch = t & 63, g = t >> 6;
  float a0 = 0.f, a1 = 0.f;
  int c = g;
  for (; c + 4 < nlist; c += 8) {
    float w0 = vf[c], w1 = vf[c + 4];
    const float* K0 = K + (size_t)js[c] * OC;
    const float* K1 = K + (size_t)js[c + 4] * OC;
    float k00 = K0[ch], k01 = K0[64 + ch];
    float k10 = K1[ch], k11 = K1[64 + ch];
    a0 = fmaf(w0, k00, a0); a1 = fmaf(w0, k01, a1);
    a0 = fmaf(w1, k10, a0); a1 = fmaf(w1, k11, a1);
  }
  for (; c < nlist; c += 4) {
    float w = vf[c];
    const float* Kr = K + (size_t)js[c] * OC;
    a0 = fmaf(w, Kr[ch], a0);
    a1 = fmaf(w, Kr[64 + ch], a1);
  }
  hpart[g][ch] = a0;
  hpart[g][64 + ch] = a1;
  __syncthreads();
  if (t < 128) {
    float hv = (hpart[0][t] + hpart[1][t]) + (hpart[2][t] + hpart[3][t]);
    H[(size_t)i * OC + t] = hv / sumw;
  }
}

extern "C" void kernel_launch(void* const* d_in, const int* in_sizes, int n_in,
                              void* d_out, int out_size, void* d_ws, size_t ws_size,
                              hipStream_t stream) {
  const float* X    = (const float*)d_in[0];
  const int*   A    = (const int*)d_in[1];
  const float* U    = (const float*)d_in[2];
  const float* W    = (const float*)d_in[3];
  const float* a1   = (const float*)d_in[4];
  const float* a2   = (const float*)d_in[5];
  const float* lmbd = (const float*)d_in[6];
  float* H = (float*)d_out;

  const size_t wt_bytes  = (size_t)IC * OC * 4;
  const size_t aux_bytes = (size_t)(7 * NN + 2 * IC + 2) * 8 + (size_t)(2 * NB + NN) * 4;
  char* base = (char*)d_ws;

  int nsplit = 8;
  while (nsplit > 1 &&
         (size_t)(nsplit + 1) * NNOC * 4 + wt_bytes + aux_bytes > ws_size)
    nsplit >>= 1;

  float* Kp = (float*)base;
  float* Kf = (nsplit > 1) ? (float*)(base + (size_t)nsplit * NNOC * 4) : Kp;
  size_t koff = (size_t)(nsplit > 1 ? nsplit + 1 : 1) * NNOC * 4;
  float* Wt = (float*)(base + koff);
  double* dbl = (double*)(base + koff + wt_bytes);
  double* k1  = dbl;            // NN
  double* k2  = k1 + NN;        // NN
  double* u1  = k2 + NN;        // NN
  double* sC  = u1 + NN;        // NN
  double* p   = sC + NN;        // NN
  double* q   = p  + NN;        // NN
  double* kvd = q  + NN;        // NN
  double* w1  = kvd + NN;       // IC
  double* w2  = w1 + IC;        // IC
  double* hdr = w2 + IC;        // 2
  int* hist    = (int*)(hdr + 2);  // NB
  int* offb    = hist + NB;        // NB
  int* sortedj = offb + NB;        // NN

  const int chunk = (IC + nsplit - 1) / nsplit;

  zero_ws2<<<(2 * NN + 255) / 256, 256, 0, stream>>>(u1, 2 * NN, hist, NB);
  wvec<<<(IC + 255) / 256, 256, 0, stream>>>(W, a1, a2, w1, w2);
  transposeW<<<dim3((IC + 31) / 32, OC / 32), 256, 0, stream>>>(W, Wt);
  xw<<<NN / 4, 256, 0, stream>>>(X, w1, w2, k1, k2);
  gemmK<<<dim3((NN + 31) / 32, nsplit), 256, 0, stream>>>(X, Wt, Kp, chunk);
  if (nsplit > 1)
    mergeK<<<(int)((NNOC / 4 + 255) / 256), 256, 0, stream>>>((const float4*)Kp, (float4*)Kf, nsplit);
  ut_reduce<<<dim3((NV + 255) / 256, (NN + 31) / 32), 256, 0, stream>>>((const float4*)U, k1, u1, sC);
  uv_kernel<<<NN / 4, 256, 0, stream>>>((const float4*)U, (const float4*)lmbd,
                                        (const double2*)u1, (const double2*)sC, p, q);
  minmax_k2<<<1, 256, 0, stream>>>(k2, hdr);
  hist_k2<<<(NN + 255) / 256, 256, 0, stream>>>(k2, hdr, hist);
  scan_hist<<<1, 1024, 0, stream>>>(hist, offb);
  scatter_k2<<<(NN + 255) / 256, 256, 0, stream>>>(k2, hdr, offb, sortedj, kvd);
  softmaxH<<<NN, 256, 0, stream>>>(A, p, q, kvd, sortedj, hdr, Kf, H);
}

// Round 9
// 272.260 us; speedup vs baseline: 3.5229x; 1.0483x over previous
//
#include <hip/hip_runtime.h>
#include <math.h>

#define NN 2708
#define IC 1433
#define OC 128
#define NV (NN / 4)          // 677 float4/int4 per row (exact)
#define NNOC ((size_t)NN * OC)
#define NB 4096              // sort buckets
#define NW 85                // ceil(NN/32) bitmap words per row

// ---------------- bitmap of A (bit j of word w = A[i][32w+j]!=0) + zero u1/sC ----------------
__global__ __launch_bounds__(256) void bitmapA_zero(const int* __restrict__ A, unsigned* __restrict__ bm,
                                                    double* __restrict__ zd, int nzd) {
  int gid = blockIdx.x * 256 + threadIdx.x;
  if (gid < nzd) zd[gid] = 0.0;
  const int total = NN * NW;
  if (gid >= total) return;
  int i = gid / NW, w = gid - i * NW;
  const int* Ar = A + (size_t)i * NN + w * 32;
  unsigned word = 0;
  if (w < NW - 1) {
    const int4* a4 = (const int4*)Ar;      // NN%4==0 and 32|w*32 -> 16B aligned
#pragma unroll
    for (int u = 0; u < 8; u++) {
      int4 a = a4[u];
      word |= (a.x != 0 ? 1u : 0u) << (4 * u);
      word |= (a.y != 0 ? 1u : 0u) << (4 * u + 1);
      word |= (a.z != 0 ? 1u : 0u) << (4 * u + 2);
      word |= (a.w != 0 ? 1u : 0u) << (4 * u + 3);
    }
  } else {
    const int nbits = NN - w * 32;         // 20 for the last word
    for (int b = 0; b < nbits; b++) word |= (Ar[b] != 0 ? 1u : 0u) << b;
  }
  bm[(size_t)i * NW + w] = word;
}

// ---------------- Wt[k][o] = W[o][k] (32x32 LDS tile transpose) ----------------
__global__ __launch_bounds__(256) void transposeW(const float* __restrict__ W, float* __restrict__ Wt) {
  __shared__ float tile[32][33];
  const int t = threadIdx.x;
  const int k0 = blockIdx.x * 32, o0 = blockIdx.y * 32;
#pragma unroll
  for (int it = 0; it < 4; it++) {
    int ro = (t >> 5) + it * 8;
    int k  = k0 + (t & 31);
    tile[ro][t & 31] = (k < IC) ? W[(size_t)(o0 + ro) * IC + k] : 0.f;
  }
  __syncthreads();
#pragma unroll
  for (int it = 0; it < 4; it++) {
    int rk = (t >> 5) + it * 8;
    int k  = k0 + rk;
    if (k < IC) Wt[(size_t)k * OC + o0 + (t & 31)] = tile[t & 31][rk];
  }
}

// ---------------- w1 = W^T a1, w2 = W^T a2 from Wt (fp64, one wave per column c) ----------------
__global__ __launch_bounds__(256) void wvec_t(const float* __restrict__ Wt, const float* __restrict__ a1,
                                              const float* __restrict__ a2,
                                              double* __restrict__ w1, double* __restrict__ w2) {
  const int t = threadIdx.x;
  const int wv = t >> 6, lane = t & 63;
  const int c = blockIdx.x * 4 + wv;
  if (c >= IC) return;
  const float* Wr = Wt + (size_t)c * OC;
  double wa = (double)Wr[lane], wb = (double)Wr[64 + lane];
  double s1 = fma(wa, (double)a1[lane], wb * (double)a1[64 + lane]);
  double s2 = fma(wa, (double)a2[lane], wb * (double)a2[64 + lane]);
  for (int o = 32; o; o >>= 1) { s1 += __shfl_down(s1, o, 64); s2 += __shfl_down(s2, o, 64); }
  if (lane == 0) { w1[c] = s1; w2[c] = s2; }
}

// ---------------- k1 = X@w1, k2 = X@w2 (fp64), one wave per row ----------------
__global__ __launch_bounds__(256) void xw(const float* __restrict__ X, const double* __restrict__ w1,
                                          const double* __restrict__ w2,
                                          double* __restrict__ k1, double* __restrict__ k2) {
  __shared__ double w1s[IC];
  __shared__ double w2s[IC];
  const int t = threadIdx.x;
  for (int c = t; c < IC; c += 256) { w1s[c] = w1[c]; w2s[c] = w2[c]; }
  __syncthreads();
  const int wave = t >> 6, lane = t & 63;
  const int i = blockIdx.x * 4 + wave;
  if (i >= NN) return;
  const float* Xi = X + (size_t)i * IC;
  double s1 = 0.0, s2 = 0.0;
  for (int c = lane; c < IC; c += 64) {
    double x = (double)Xi[c];
    s1 = fma(x, w1s[c], s1);
    s2 = fma(x, w2s[c], s2);
  }
  for (int o = 32; o; o >>= 1) { s1 += __shfl_down(s1, o, 64); s2 += __shfl_down(s2, o, 64); }
  if (lane == 0) { k1[i] = s1; k2[i] = s2; }
}

// ---------------- K partials: Kp[split] = X @ Wt over k-chunk (fp32, conflict-free LDS) ----------------
__global__ __launch_bounds__(256) void gemmK(const float* __restrict__ X, const float* __restrict__ Wt,
                                             float* __restrict__ Kp, int chunk) {
  __shared__ float Xs[32][36];
  __shared__ float Ws[32][132];
  const int t  = threadIdx.x;
  const int rb = blockIdx.x * 32;
  const int ks = blockIdx.y * chunk;
  const int ke = min(IC, ks + chunk);
  float* __restrict__ Ko = Kp + (size_t)blockIdx.y * NNOC;
  const int row0 = (t >> 5) * 4;
  const int col4 = (t & 31) * 4;
  float acc[4][4];
#pragma unroll
  for (int r = 0; r < 4; r++)
#pragma unroll
    for (int c = 0; c < 4; c++) acc[r][c] = 0.f;

  for (int kb = ks; kb < ke; kb += 32) {
#pragma unroll
    for (int it = 0; it < 4; it++) {
      int idx = t + it * 256;
      int r = idx >> 5, c = idx & 31;
      int gr = rb + r, gc = kb + c;
      Xs[r][c] = (gr < NN && gc < ke) ? X[(size_t)gr * IC + gc] : 0.f;
    }
#pragma unroll
    for (int it = 0; it < 4; it++) {
      int idx4 = t + it * 256;
      int k = idx4 >> 5, cg = (idx4 & 31) * 4;
      int gk = kb + k;
      float4 v = make_float4(0.f, 0.f, 0.f, 0.f);
      if (gk < ke) v = *reinterpret_cast<const float4*>(&Wt[(size_t)gk * OC + cg]);
      *reinterpret_cast<float4*>(&Ws[k][cg]) = v;
    }
    __syncthreads();
#pragma unroll
    for (int g = 0; g < 8; g++) {
      float xr[4][4];
#pragma unroll
      for (int r = 0; r < 4; r++)
        *reinterpret_cast<float4*>(xr[r]) = *reinterpret_cast<const float4*>(&Xs[row0 + r][g * 4]);
#pragma unroll
      for (int j = 0; j < 4; j++) {
        const float4 w4 = *reinterpret_cast<const float4*>(&Ws[g * 4 + j][col4]);
#pragma unroll
        for (int r = 0; r < 4; r++) {
          acc[r][0] = fmaf(xr[r][j], w4.x, acc[r][0]);
          acc[r][1] = fmaf(xr[r][j], w4.y, acc[r][1]);
          acc[r][2] = fmaf(xr[r][j], w4.z, acc[r][2]);
          acc[r][3] = fmaf(xr[r][j], w4.w, acc[r][3]);
        }
      }
    }
    __syncthreads();
  }
#pragma unroll
  for (int r = 0; r < 4; r++) {
    int gr = rb + row0 + r;
    if (gr < NN) {
      float4 v = make_float4(acc[r][0], acc[r][1], acc[r][2], acc[r][3]);
      *reinterpret_cast<float4*>(&Ko[(size_t)gr * OC + col4]) = v;
    }
  }
}

// ---------------- merge split-K partials (float4, nsplit-generic) ----------------
__global__ __launch_bounds__(256) void mergeK(const float4* __restrict__ Kp, float4* __restrict__ Kf, int nsplit) {
  size_t i = (size_t)blockIdx.x * 256 + threadIdx.x;
  const size_t n4 = NNOC / 4;
  if (i >= n4) return;
  float4 s = Kp[i];
  for (int ps = 1; ps < nsplit; ps++) {
    float4 v = Kp[(size_t)ps * n4 + i];
    s.x += v.x; s.y += v.y; s.z += v.z; s.w += v.w;
  }
  Kf[i] = s;
}

// ---------------- u1 = U^T@k1, s = U^T@1 (fp64, float4 cols) ----------------
__global__ __launch_bounds__(256) void ut_reduce(const float4* __restrict__ U4, const double* __restrict__ k1,
                                                 double* __restrict__ u1, double* __restrict__ s) {
  int c4 = blockIdx.x * 256 + threadIdx.x;
  if (c4 >= NV) return;
  int r0 = blockIdx.y * 32;
  int r1 = min(NN, r0 + 32);
  double au0 = 0, au1_ = 0, au2 = 0, au3 = 0, as0 = 0, as1 = 0, as2 = 0, as3 = 0;
  for (int r = r0; r < r1; r++) {
    float4 u = U4[(size_t)r * NV + c4];
    double kr = k1[r];
    au0 = fma((double)u.x, kr, au0); au1_ = fma((double)u.y, kr, au1_);
    au2 = fma((double)u.z, kr, au2); au3 = fma((double)u.w, kr, au3);
    as0 += (double)u.x; as1 += (double)u.y; as2 += (double)u.z; as3 += (double)u.w;
  }
  int c = c4 * 4;
  atomicAdd(&u1[c + 0], au0); atomicAdd(&u1[c + 1], au1_);
  atomicAdd(&u1[c + 2], au2); atomicAdd(&u1[c + 3], au3);
  atomicAdd(&s[c + 0], as0);  atomicAdd(&s[c + 1], as1);
  atomicAdd(&s[c + 2], as2);  atomicAdd(&s[c + 3], as3);
}

// ---------------- p = U@(lmbd*u1), q = U@(lmbd*s) (fp64), one wave per row ----------------
__global__ __launch_bounds__(256) void uv_kernel(const float4* __restrict__ U4, const float4* __restrict__ L4,
                                                 const double2* __restrict__ u1d, const double2* __restrict__ sd,
                                                 double* __restrict__ p, double* __restrict__ q) {
  const int t = threadIdx.x;
  const int wave = t >> 6, lane = t & 63;
  const int r = blockIdx.x * 4 + wave;
  if (r >= NN) return;
  const float4* Ur = U4 + (size_t)r * NV;
  double ap = 0.0, aq = 0.0;
  for (int c4 = lane; c4 < NV; c4 += 64) {
    float4 u = Ur[c4];
    float4 lm = L4[c4];
    double2 ua = u1d[c4 * 2], ub = u1d[c4 * 2 + 1];
    double2 sa = sd[c4 * 2],  sb = sd[c4 * 2 + 1];
    ap = fma((double)u.x, (double)lm.x * ua.x, ap);
    ap = fma((double)u.y, (double)lm.y * ua.y, ap);
    ap = fma((double)u.z, (double)lm.z * ub.x, ap);
    ap = fma((double)u.w, (double)lm.w * ub.y, ap);
    aq = fma((double)u.x, (double)lm.x * sa.x, aq);
    aq = fma((double)u.y, (double)lm.y * sa.y, aq);
    aq = fma((double)u.z, (double)lm.z * sb.x, aq);
    aq = fma((double)u.w, (double)lm.w * sb.y, aq);
  }
  for (int o = 32; o; o >>= 1) { ap += __shfl_down(ap, o, 64); aq += __shfl_down(aq, o, 64); }
  if (lane == 0) { p[r] = ap; q[r] = aq; }
}

// ---------------- fused bucket sort of k2 (one block): minmax + hist + scan + scatter ----------------
__global__ __launch_bounds__(1024) void sortk2(const double* __restrict__ k2,
                                               double* __restrict__ kvd, int* __restrict__ sortedj,
                                               double* __restrict__ hdr) {
  __shared__ int hist[NB];          // 16 KB
  __shared__ int ps[1024];
  __shared__ double rmn[16], rmx[16];
  __shared__ double mn_sh, sc_sh;
  const int t = threadIdx.x, wv = t >> 6, ln = t & 63;

  double mn = 1e300, mx = -1e300;
  for (int j = t; j < NN; j += 1024) { double v = k2[j]; mn = fmin(mn, v); mx = fmax(mx, v); }
  for (int o = 32; o; o >>= 1) { mn = fmin(mn, __shfl_xor(mn, o, 64)); mx = fmax(mx, __shfl_xor(mx, o, 64)); }
  if (ln == 0) { rmn[wv] = mn; rmx[wv] = mx; }
  for (int b = t; b < NB; b += 1024) hist[b] = 0;
  __syncthreads();
  if (t == 0) {
    double amn = rmn[0], amx = rmx[0];
    for (int u = 1; u < 16; u++) { amn = fmin(amn, rmn[u]); amx = fmax(amx, rmx[u]); }
    hdr[0] = amn; hdr[1] = amx;
    mn_sh = amn; sc_sh = NB / fmax(amx - amn, 1e-30);
  }
  __syncthreads();
  const double minv = mn_sh, scale = sc_sh;
  for (int j = t; j < NN; j += 1024) {
    int b = min(NB - 1, max(0, (int)((k2[j] - minv) * scale)));
    atomicAdd(&hist[b], 1);
  }
  __syncthreads();
  int4 v4 = ((const int4*)hist)[t];
  int s = v4.x + v4.y + v4.z + v4.w;
  ps[t] = s;
  __syncthreads();
  for (int d = 1; d < 1024; d <<= 1) {
    int x = (t >= d) ? ps[t - d] : 0;
    __syncthreads();
    ps[t] += x;
    __syncthreads();
  }
  int excl = ps[t] - s;
  hist[4 * t]     = excl;
  hist[4 * t + 1] = excl + v4.x;
  hist[4 * t + 2] = excl + v4.x + v4.y;
  hist[4 * t + 3] = excl + v4.x + v4.y + v4.z;
  __syncthreads();
  for (int j = t; j < NN; j += 1024) {
    double v = k2[j];
    int b = min(NB - 1, max(0, (int)((v - minv) * scale)));
    int pos = atomicAdd(&hist[b], 1);
    kvd[pos] = v;
    sortedj[pos] = j;
  }
}

// ---------------- softmax+H: sorted-tail walk with bitmap probes, one block per row ----------------
__global__ __launch_bounds__(256) void softmaxH(const unsigned* __restrict__ bm,
                                                const double* __restrict__ p, const double* __restrict__ q,
                                                const double* __restrict__ kvd, const int* __restrict__ sortedj,
                                                const double* __restrict__ hdr,
                                                const float* __restrict__ K, float* __restrict__ H) {
  __shared__ float vf[NN];
  __shared__ short js[NN];
  __shared__ float hpart[4][128];
  __shared__ int wcnt[4];
  __shared__ double wfv[4], wbnd[4];
  __shared__ float redf[4];

  const int i = blockIdx.x;
  const int t = threadIdx.x;
  const int wv = t >> 6, lane = t & 63;
  const double pi = p[i], qi = q[i];
  const double bw = (hdr[1] - hdr[0]) * (1.0 / NB);
  const double margin = 36.0 + 2.0 * fabs(qi) * bw;
  const unsigned* bmrow = bm + (size_t)i * NW;
  const bool sgn = (qi >= 0.0);
  const unsigned long long ltmask = (1ull << lane) - 1ull;
  int nlist = 0;
  double m_lb = -1e300;

  int coveredA = 0;
  for (int r = 0; r * 256 < NN; r++) {
    int idx = r * 256 + t;
    bool ok = idx < NN;
    double v = 0.0; int j = 0; unsigned a = 0;
    if (ok) {
      int pos = sgn ? (NN - 1 - idx) : idx;
      v = fma(qi, kvd[pos], pi);
      j = sortedj[pos];
      a = (bmrow[j >> 5] >> (j & 31)) & 1u;
    }
    bool isn = ok && a;
    unsigned long long mask = __ballot(isn);
    int wo = __popcll(mask & ltmask);
    double fv = isn ? fabs(v) : -1e300;
    double bnd = ok ? v : 1e300;
    for (int o = 32; o; o >>= 1) {
      fv = fmax(fv, __shfl_xor(fv, o, 64));
      bnd = fmin(bnd, __shfl_xor(bnd, o, 64));
    }
    if (lane == 0) { wcnt[wv] = __popcll(mask); wfv[wv] = fv; wbnd[wv] = bnd; }
    __syncthreads();
    int c0 = wcnt[0], c1 = wcnt[1], c2 = wcnt[2], c3 = wcnt[3];
    int base = nlist + (wv > 0 ? c0 : 0) + (wv > 1 ? c1 : 0) + (wv > 2 ? c2 : 0);
    if (isn) { js[base + wo] = (short)j; vf[base + wo] = (float)v; }
    nlist += c0 + c1 + c2 + c3;
    m_lb = fmax(m_lb, fmax(fmax(wfv[0], wfv[1]), fmax(wfv[2], wfv[3])));
    double rbnd = fmin(fmin(wbnd[0], wbnd[1]), fmin(wbnd[2], wbnd[3]));
    __syncthreads();
    coveredA = min(NN, (r + 1) * 256);
    if (rbnd < m_lb - margin) break;
  }
  const int remB = NN - coveredA;

  for (int r = 0; r * 256 < remB; r++) {
    int idx = r * 256 + t;
    bool ok = idx < remB;
    double v = 0.0; int j = 0; unsigned a = 0;
    if (ok) {
      int pos = sgn ? idx : (NN - 1 - idx);
      v = fma(qi, kvd[pos], pi);
      j = sortedj[pos];
      a = (bmrow[j >> 5] >> (j & 31)) & 1u;
    }
    bool isn = ok && a;
    unsigned long long mask = __ballot(isn);
    int wo = __popcll(mask & ltmask);
    double fv = isn ? fabs(v) : -1e300;
    double bnd = ok ? v : -1e300;
    for (int o = 32; o; o >>= 1) {
      fv = fmax(fv, __shfl_xor(fv, o, 64));
      bnd = fmax(bnd, __shfl_xor(bnd, o, 64));
    }
    if (lane == 0) { wcnt[wv] = __popcll(mask); wfv[wv] = fv; wbnd[wv] = bnd; }
    __syncthreads();
    int c0 = wcnt[0], c1 = wcnt[1], c2 = wcnt[2], c3 = wcnt[3];
    int base = nlist + (wv > 0 ? c0 : 0) + (wv > 1 ? c1 : 0) + (wv > 2 ? c2 : 0);
    if (isn) { js[base + wo] = (short)j; vf[base + wo] = (float)v; }
    nlist += c0 + c1 + c2 + c3;
    m_lb = fmax(m_lb, fmax(fmax(wfv[0], wfv[1]), fmax(wfv[2], wfv[3])));
    double rbnd = fmax(fmax(wbnd[0], wbnd[1]), fmax(wbnd[2], wbnd[3]));
    __syncthreads();
    if (-rbnd < m_lb - margin) break;
  }

  const float fm = (float)m_lb;
  float sw = 0.f;
  for (int c = t; c < nlist; c += 256) {
    float w = __expf(fabsf(vf[c]) - fm);
    vf[c] = w;
    sw += w;
  }
  for (int o = 32; o; o >>= 1) sw += __shfl_xor(sw, o, 64);
  if (lane == 0) redf[wv] = sw;
  __syncthreads();
  const float sumw = (redf[0] + redf[1]) + (redf[2] + redf[3]);

  const int ch = t & 63, g = t >> 6;
  float a0 = 0.f, a1 = 0.f;
  int c = g;
  for (; c + 4 < nlist; c += 8) {
    float w0 = vf[c], w1 = vf[c + 4];
    const float* K0 = K + (size_t)js[c] * OC;
    const float* K1 = K + (size_t)js[c + 4] * OC;
    float k00 = K0[ch], k01 = K0[64 + ch];
    float k10 = K1[ch], k11 = K1[64 + ch];
    a0 = fmaf(w0, k00, a0); a1 = fmaf(w0, k01, a1);
    a0 = fmaf(w1, k10, a0); a1 = fmaf(w1, k11, a1);
  }
  for (; c < nlist; c += 4) {
    float w = vf[c];
    const float* Kr = K + (size_t)js[c] * OC;
    a0 = fmaf(w, Kr[ch], a0);
    a1 = fmaf(w, Kr[64 + ch], a1);
  }
  hpart[g][ch] = a0;
  hpart[g][64 + ch] = a1;
  __syncthreads();
  if (t < 128) {
    float hv = (hpart[0][t] + hpart[1][t]) + (hpart[2][t] + hpart[3][t]);
    H[(size_t)i * OC + t] = hv / sumw;
  }
}

extern "C" void kernel_launch(void* const* d_in, const int* in_sizes, int n_in,
                              void* d_out, int out_size, void* d_ws, size_t ws_size,
                              hipStream_t stream) {
  const float* X    = (const float*)d_in[0];
  const int*   A    = (const int*)d_in[1];
  const float* U    = (const float*)d_in[2];
  const float* W    = (const float*)d_in[3];
  const float* a1   = (const float*)d_in[4];
  const float* a2   = (const float*)d_in[5];
  const float* lmbd = (const float*)d_in[6];
  float* H = (float*)d_out;

  const size_t wt_bytes  = (size_t)IC * OC * 4;
  const size_t bm_bytes  = (size_t)NN * NW * 4;
  const size_t aux_bytes = (size_t)(7 * NN + 2 * IC + 2) * 8 + (size_t)NN * 4 + bm_bytes + 256;
  char* base = (char*)d_ws;

  int nsplit = 8;
  while (nsplit > 1 &&
         (size_t)(nsplit + 1) * NNOC * 4 + wt_bytes + aux_bytes > ws_size)
    nsplit >>= 1;

  float* Kp = (float*)base;
  float* Kf = (nsplit > 1) ? (float*)(base + (size_t)nsplit * NNOC * 4) : Kp;
  size_t koff = (size_t)(nsplit > 1 ? nsplit + 1 : 1) * NNOC * 4;
  float* Wt = (float*)(base + koff);
  double* dbl = (double*)(base + koff + wt_bytes);
  double* k1  = dbl;            // NN
  double* k2  = k1 + NN;        // NN
  double* u1  = k2 + NN;        // NN
  double* sC  = u1 + NN;        // NN
  double* p   = sC + NN;        // NN
  double* q   = p  + NN;        // NN
  double* kvd = q  + NN;        // NN
  double* w1  = kvd + NN;       // IC
  double* w2  = w1 + IC;        // IC
  double* hdr = w2 + IC;        // 2
  int* sortedj = (int*)(hdr + 2);       // NN
  unsigned* bm = (unsigned*)(sortedj + NN);  // NN*NW

  const int chunk = (IC + nsplit - 1) / nsplit;

  bitmapA_zero<<<(NN * NW + 255) / 256, 256, 0, stream>>>(A, bm, u1, 2 * NN);
  transposeW<<<dim3((IC + 31) / 32, OC / 32), 256, 0, stream>>>(W, Wt);
  wvec_t<<<(IC + 3) / 4, 256, 0, stream>>>(Wt, a1, a2, w1, w2);
  xw<<<NN / 4, 256, 0, stream>>>(X, w1, w2, k1, k2);
  gemmK<<<dim3((NN + 31) / 32, nsplit), 256, 0, stream>>>(X, Wt, Kp, chunk);
  if (nsplit > 1)
    mergeK<<<(int)((NNOC / 4 + 255) / 256), 256, 0, stream>>>((const float4*)Kp, (float4*)Kf, nsplit);
  ut_reduce<<<dim3((NV + 255) / 256, (NN + 31) / 32), 256, 0, stream>>>((const float4*)U, k1, u1, sC);
  uv_kernel<<<NN / 4, 256, 0, stream>>>((const float4*)U, (const float4*)lmbd,
                                        (const double2*)u1, (const double2*)sC, p, q);
  sortk2<<<1, 1024, 0, stream>>>(k2, kvd, sortedj, hdr);
  softmaxH<<<NN, 256, 0, stream>>>(bm, p, q, kvd, sortedj, hdr, Kf, H);
}